// Round 1
// baseline (5443.187 us; speedup 1.0000x reference)
//
#include <hip/hip_runtime.h>

#define Bz 8
#define T1z 13
#define Tz 12
#define Vz 20000
#define Ez 512
#define Dz 512
#define Kz 512
#define Cz 2048
#define Pz 64
#define NB 256
#define NT 512

// ---- persistent-kernel grid barrier state (device globals persist across graph replays;
//      sense is a monotone generation counter so no reset is needed) ----
__device__ unsigned g_slots[NB];
__device__ unsigned g_gen2;

__device__ __forceinline__ float waveReduce(float v) {
    #pragma unroll
    for (int off = 32; off > 0; off >>= 1) v += __shfl_xor(v, off);
    return v;
}

__device__ __forceinline__ float sigf(float x) { return 1.0f / (1.0f + expf(-x)); }

// Grid-wide barrier: every block publishes its arrival in its own slot (no atomic
// contention); block 0's wave 0 polls all 256 slots and releases the generation.
// Guard valves bound the spin so a residency failure degrades instead of hanging.
__device__ __forceinline__ void gridSync(unsigned target) {
    __syncthreads();
    if (threadIdx.x == 0) {
        __threadfence();
        __hip_atomic_store(&g_slots[blockIdx.x], target, __ATOMIC_RELEASE, __HIP_MEMORY_SCOPE_AGENT);
    }
    if (blockIdx.x == 0) {
        if (threadIdx.x < 64) {
            long guard = 0;
            for (;;) {
                bool ok = true;
                #pragma unroll
                for (int i = 0; i < 4; i++) {
                    unsigned v = __hip_atomic_load(&g_slots[threadIdx.x + i * 64],
                                                   __ATOMIC_ACQUIRE, __HIP_MEMORY_SCOPE_AGENT);
                    ok = ok && ((int)(v - target) >= 0);
                }
                if (__all(ok)) break;
                __builtin_amdgcn_s_sleep(1);
                if (++guard > (1L << 20)) break;
            }
            if (threadIdx.x == 0) {
                __threadfence();
                __hip_atomic_store(&g_gen2, target, __ATOMIC_RELEASE, __HIP_MEMORY_SCOPE_AGENT);
            }
        }
    } else if (threadIdx.x == 0) {
        long guard = 0;
        while ((int)(__hip_atomic_load(&g_gen2, __ATOMIC_ACQUIRE, __HIP_MEMORY_SCOPE_AGENT) - target) < 0) {
            __builtin_amdgcn_s_sleep(1);
            if (++guard > (1L << 20)) break;
        }
        __threadfence();
    }
    __syncthreads();
}

__global__ __launch_bounds__(NT, 2) void k_main(
    const float* __restrict__ enc, const int* __restrict__ caps, const int* __restrict__ caplen,
    const float* __restrict__ W_c, const float* __restrict__ b_c, const float* __restrict__ W_i_hat,
    const float* __restrict__ W_s, const float* __restrict__ b_s, const float* __restrict__ W_i,
    const float* __restrict__ emb,
    const float* __restrict__ W_ih, const float* __restrict__ W_hh,
    const float* __restrict__ b_ih, const float* __restrict__ b_hh,
    const float* __restrict__ W_init_h, const float* __restrict__ b_init_h,
    const float* __restrict__ W_init_c, const float* __restrict__ b_init_c,
    const float* __restrict__ W_hc, const float* __restrict__ W_hs,
    const float* __restrict__ W_fc, const float* __restrict__ b_fc,
    float* __restrict__ out, float* __restrict__ ws)
{
    // 24832 floats = 99,328 B of LDS (one block per CU; max gfx950 WG LDS is 160 KiB)
    __shared__ __align__(16) float smemf[24832];

    float* vmean  = ws;                     // 16384
    float* hbuf   = vmean + 16384;          // 4096
    float* cbuf   = hbuf + 4096;            // 4096
    float* qpart  = cbuf + 4096;            // 4ch*2which*8b*512k = 32768
    float* beta   = qpart + 32768;          // 16384
    float* scoreS = beta + 16384;           // 512  [b][p]
    float* xcat   = scoreS + 512;           // 8*3072 = 24576
    float* hhist  = xcat + 24576;           // 96*512 = 49152
    float* spart  = hhist + 49152;          // 32*8*64*512 = 8388608

    const int tid  = threadIdx.x;
    const int bid  = blockIdx.x;
    const int lane = tid & 63;
    const int bw   = tid >> 6;              // wave in block: 0..7
    const int gw   = bid * 8 + bw;          // global wave: 0..2047

    unsigned bt = __hip_atomic_load(&g_gen2, __ATOMIC_RELAXED, __HIP_MEMORY_SCOPE_AGENT);

    // ================= phase 0: tail fills + Vmean =================
    {
        int gid = bid * NT + tid;
        const int base = Bz * Tz * Vz;
        const int nCap = Bz * T1z;          // 104
        const int nAlp = Bz * Tz * Pz;      // 6144
        if (gid < nCap + Bz + nAlp + Bz) {
            if (gid < nCap) out[base + gid] = (float)caps[gid];
            else if (gid < nCap + Bz) out[base + gid] = (float)(caplen[gid - nCap] - 1);
            else if (gid < nCap + Bz + nAlp) out[base + gid] = 0.0f;
            else out[base + gid] = (float)(gid - (nCap + Bz + nAlp));
        }
        #pragma unroll
        for (int j = 0; j < 8; j++) {
            int w = gw * 8 + j;             // (b*Cz + c), 0..16383
            float v = enc[(size_t)w * 64 + lane];
            v = waveReduce(v);
            if (lane == 0) vmean[w] = v * (1.0f / 64.0f);
        }
    }
    gridSync(++bt);

    // ================= phase 1: h0 / c0 =================
    {
        #pragma unroll
        for (int j = 0; j < 4; j++) {
            int o = gw * 4 + j;             // 0..8191
            int which = o >> 12;
            int rem = o & 4095;
            int b = rem >> 9, d = rem & 511;
            const float* W = which ? W_init_c : W_init_h;
            float acc = 0.0f;
            #pragma unroll 4
            for (int i = 0; i < 32; i++) {
                int cc = i * 64 + lane;
                acc = fmaf(vmean[b * Cz + cc], W[(size_t)d * Cz + cc], acc);
            }
            acc = waveReduce(acc);
            if (lane == 0) {
                if (which) cbuf[rem] = acc + b_init_c[d];
                else       hbuf[rem] = acc + b_init_h[d];
            }
        }
    }
    gridSync(++bt);

    for (int t = 0; t < Tz; t++) {
        // ========== A: q projections (h@W_hc, h@W_hs; d-split 4) + zero scoreS ==========
        {
            int gid = bid * NT + tid;
            if (gid < 32768) {
                int k = gid & 511;
                int r = gid >> 9;           // 0..63
                int b = r & 7, which = (r >> 3) & 1, ch = r >> 4;
                const float* W = which ? W_hs : W_hc;
                const float* hb = hbuf + b * Dz;
                float acc = 0.0f;
                int d0 = ch * 128;
                #pragma unroll 8
                for (int d = d0; d < d0 + 128; d++) acc = fmaf(hb[d], W[(size_t)d * Kz + k], acc);
                qpart[(size_t)r * Kz + k] = acc;
            } else if (gid < 32768 + 512) {
                scoreS[gid - 32768] = 0.0f;
            }
        }
        gridSync(++bt);

        // ========== B: channel attention scores + batch softmax -> beta ==========
        // block handles c in [bid*8, bid*8+8); wave bw == batch b; q cached in regs
        {
            float* sL = smemf;              // [8 c][8 b]
            int b = bw;
            const float4* qp4 = (const float4*)qpart;
            const float4* wc4 = (const float4*)W_c;
            const float4* bc4 = (const float4*)b_c;
            const float4* wi4 = (const float4*)W_i_hat;
            int k0 = lane, k1 = 64 + lane;
            float4 q0 = bc4[k0], q1 = bc4[k1];
            #pragma unroll
            for (int ch = 0; ch < 4; ch++) {
                float4 a = qp4[((ch * 2) * Bz + b) * 128 + k0];
                float4 e = qp4[((ch * 2) * Bz + b) * 128 + k1];
                q0.x += a.x; q0.y += a.y; q0.z += a.z; q0.w += a.w;
                q1.x += e.x; q1.y += e.y; q1.z += e.z; q1.w += e.w;
            }
            float4 wcA = wc4[k0], wcB = wc4[k1];
            float4 wiA = wi4[k0], wiB = wi4[k1];
            #pragma unroll
            for (int j = 0; j < 8; j++) {
                int cc = bid * 8 + j;
                float v = vmean[b * Cz + cc];
                float acc = 0.0f;
                acc += tanhf(fmaf(v, wcA.x, q0.x)) * wiA.x;
                acc += tanhf(fmaf(v, wcA.y, q0.y)) * wiA.y;
                acc += tanhf(fmaf(v, wcA.z, q0.z)) * wiA.z;
                acc += tanhf(fmaf(v, wcA.w, q0.w)) * wiA.w;
                acc += tanhf(fmaf(v, wcB.x, q1.x)) * wiB.x;
                acc += tanhf(fmaf(v, wcB.y, q1.y)) * wiB.y;
                acc += tanhf(fmaf(v, wcB.z, q1.z)) * wiB.z;
                acc += tanhf(fmaf(v, wcB.w, q1.w)) * wiB.w;
                acc = waveReduce(acc);
                if (lane == 0) sL[j * 8 + b] = acc;
            }
            __syncthreads();
            if (tid < 64) {
                int j = tid >> 3, b2 = tid & 7;
                float m = -1e30f;
                #pragma unroll
                for (int q = 0; q < 8; q++) m = fmaxf(m, sL[j * 8 + q]);
                float s = 0.0f;
                #pragma unroll
                for (int q = 0; q < 8; q++) s += expf(sL[j * 8 + q] - m);
                beta[b2 * Cz + bid * 8 + j] = expf(sL[j * 8 + b2] - m) / s;
            }
        }
        gridSync(++bt);

        // ========== C: partial einsum spart[sl][b][p][k] = sum_{c in slice} enc*beta*W_s ==========
        // block = (slice 0..31, b 0..7); 64p x 512k tile; 8x8 per-thread register tile
        {
            float* As = smemf;              // [32][64]  (c x p, pre-scaled by beta)
            float* Bs = smemf + 2048;       // [32][512] (c x k)
            int b = bid & 7, sl = bid >> 3;
            int kq = tid & 63, pq = tid >> 6;
            float acc[8][8];
            #pragma unroll
            for (int i = 0; i < 8; i++)
                #pragma unroll
                for (int j = 0; j < 8; j++) acc[i][j] = 0.0f;

            #pragma unroll
            for (int half = 0; half < 2; half++) {
                int c0 = sl * 64 + half * 32;
                {   // stage As: 2048 floats, 1 float4/thread
                    int cl = tid >> 4, p4 = tid & 15;
                    int cc = c0 + cl;
                    float btv = beta[b * Cz + cc];
                    float4 ev = ((const float4*)enc)[(size_t)(b * Cz + cc) * 16 + p4];
                    ((float4*)As)[cl * 16 + p4] = make_float4(ev.x * btv, ev.y * btv, ev.z * btv, ev.w * btv);
                }
                {   // stage Bs: 16384 floats, 8 float4/thread (128B segments)
                    int base4 = tid * 8;
                    int cl = base4 >> 7, kf = base4 & 127;
                    const float4* wsrc = (const float4*)(W_s + (size_t)(c0 + cl) * Kz);
                    float4* bdst = (float4*)Bs + cl * 128 + kf;
                    #pragma unroll
                    for (int j = 0; j < 8; j++) bdst[j] = wsrc[kf + j];
                }
                __syncthreads();
                #pragma unroll 4
                for (int cc = 0; cc < 32; cc++) {
                    float4 a0 = ((float4*)As)[cc * 16 + pq * 2];
                    float4 a1 = ((float4*)As)[cc * 16 + pq * 2 + 1];
                    float4 b0 = ((float4*)Bs)[cc * 128 + kq * 2];
                    float4 b1 = ((float4*)Bs)[cc * 128 + kq * 2 + 1];
                    float av[8] = {a0.x, a0.y, a0.z, a0.w, a1.x, a1.y, a1.z, a1.w};
                    float bv[8] = {b0.x, b0.y, b0.z, b0.w, b1.x, b1.y, b1.z, b1.w};
                    #pragma unroll
                    for (int i = 0; i < 8; i++)
                        #pragma unroll
                        for (int j = 0; j < 8; j++)
                            acc[i][j] = fmaf(av[i], bv[j], acc[i][j]);
                }
                __syncthreads();
            }
            float* dst = spart + (size_t)(sl * 8 + b) * 64 * 512;
            #pragma unroll
            for (int r = 0; r < 8; r++) {
                int p = pq * 8 + r;
                float4* dp = (float4*)(dst + (size_t)p * 512 + kq * 8);
                dp[0] = make_float4(acc[r][0], acc[r][1], acc[r][2], acc[r][3]);
                dp[1] = make_float4(acc[r][4], acc[r][5], acc[r][6], acc[r][7]);
            }
        }
        gridSync(++bt);

        // ========== D: spatial scores (k-split over blocks, atomicAdd into scoreS) ==========
        // block = (p 0..63, k-quarter 0..3); wave bw == b; lanes: 32 k-float4 x 2 slice-halves
        {
            int p = bid >> 2, kqr = bid & 3;
            int b = bw;
            int kf = lane & 31;
            int sh = lane >> 5;
            int kg = kqr * 32 + kf;         // global float4 index 0..127
            const float4* sp4 = (const float4*)spart;
            float sx = 0.f, sy = 0.f, sz = 0.f, sw = 0.f;
            #pragma unroll
            for (int i = 0; i < 16; i++) {
                int sl = sh * 16 + i;
                float4 tv = sp4[((size_t)(sl * 8 + b) * 64 + p) * 128 + kg];
                sx += tv.x; sy += tv.y; sz += tv.z; sw += tv.w;
            }
            sx += __shfl_xor(sx, 32); sy += __shfl_xor(sy, 32);
            sz += __shfl_xor(sz, 32); sw += __shfl_xor(sw, 32);
            float acc = 0.0f;
            if (sh == 0) {
                float4 q = ((const float4*)b_s)[kg];
                #pragma unroll
                for (int ch = 0; ch < 4; ch++) {
                    float4 tq = ((const float4*)qpart)[((ch * 2 + 1) * Bz + b) * 128 + kg];
                    q.x += tq.x; q.y += tq.y; q.z += tq.z; q.w += tq.w;
                }
                float4 wi = ((const float4*)W_i)[kg];
                acc = tanhf(sx + q.x) * wi.x + tanhf(sy + q.y) * wi.y +
                      tanhf(sz + q.z) * wi.z + tanhf(sw + q.w) * wi.w;
            }
            acc = waveReduce(acc);
            if (lane == 0) atomicAdd(&scoreS[b * 64 + p], acc);
        }
        gridSync(++bt);

        // ========== E: alpha softmax (per-wave, in-reg) + awe -> xcat; emb/h segments ==========
        {
            int b = gw >> 8;                // 8 b x 256 waves
            int cg = gw & 255;
            float sc[8];
            #pragma unroll
            for (int bb = 0; bb < 8; bb++) sc[bb] = scoreS[bb * 64 + lane];
            float m = -1e30f;
            #pragma unroll
            for (int bb = 0; bb < 8; bb++) m = fmaxf(m, sc[bb]);
            float denom = 0.0f;
            #pragma unroll
            for (int bb = 0; bb < 8; bb++) denom += expf(sc[bb] - m);
            float aval = expf(sc[b] - m) / denom;   // alpha[b][p=lane]
            #pragma unroll
            for (int j = 0; j < 8; j++) {
                int cc = cg * 8 + j;
                float e = enc[(size_t)(b * Cz + cc) * 64 + lane];
                float v = waveReduce(e * aval);
                if (lane == 0) xcat[b * 3072 + Ez + cc] = beta[b * Cz + cc] * v * (1.0f / 64.0f);
            }
            int gid = bid * NT + tid;
            if (gid < 8192) {
                int b2 = gid >> 10, r = gid & 1023;
                if (r < Ez) xcat[b2 * 3072 + r] = emb[(size_t)caps[b2 * T1z + t] * Ez + r];
                else        xcat[b2 * 3072 + 2560 + (r - Ez)] = hbuf[b2 * Dz + (r - Ez)];
            }
        }
        gridSync(++bt);

        // ========== F: gates (full 3072 contraction) + LSTM cell, fused ==========
        // block = d-pair (bid*2, bid*2+1); wave = (e-quarter q, dd); each wave does 4 gate rows
        {
            float* sx = smemf;              // xcat staged: 24576 floats
            float* gp = smemf + 24576;      // partials: [bw][g][b] = 8*4*8
            float4* sx4 = (float4*)sx;
            const float4* xc4 = (const float4*)xcat;
            #pragma unroll
            for (int i = 0; i < 12; i++) sx4[tid + i * 512] = xc4[tid + i * 512];
            __syncthreads();
            int q = bw >> 1, dd = bw & 1;
            int d2 = bid * 2 + dd;
            int b = lane >> 3, e8 = lane & 7;
            float accg[4] = {0.f, 0.f, 0.f, 0.f};
            #pragma unroll 4
            for (int i = 0; i < 24; i++) {
                int ef4 = q * 192 + i * 8 + e8;     // float4 index into 768-f4 row
                float4 xv = sx4[b * 768 + ef4];
                bool ih = (ef4 < 640);              // wave-uniform per i
                #pragma unroll
                for (int g = 0; g < 4; g++) {
                    int j = g * 512 + d2;
                    float4 w = ih ? ((const float4*)W_ih)[(size_t)j * 640 + ef4]
                                  : ((const float4*)W_hh)[(size_t)j * 128 + (ef4 - 640)];
                    accg[g] = fmaf(xv.x, w.x, accg[g]);
                    accg[g] = fmaf(xv.y, w.y, accg[g]);
                    accg[g] = fmaf(xv.z, w.z, accg[g]);
                    accg[g] = fmaf(xv.w, w.w, accg[g]);
                }
            }
            #pragma unroll
            for (int mm = 1; mm < 8; mm <<= 1) {
                #pragma unroll
                for (int g = 0; g < 4; g++) accg[g] += __shfl_xor(accg[g], mm);
            }
            if (e8 == 0) {
                #pragma unroll
                for (int g = 0; g < 4; g++) gp[(bw * 4 + g) * 8 + b] = accg[g];
            }
            __syncthreads();
            if (tid < 16) {
                int b2 = tid & 7, ddd = tid >> 3;
                int d3 = bid * 2 + ddd;
                float gate[4];
                #pragma unroll
                for (int g = 0; g < 4; g++) {
                    float sum = 0.0f;
                    #pragma unroll
                    for (int qq = 0; qq < 4; qq++) sum += gp[((qq * 2 + ddd) * 4 + g) * 8 + b2];
                    gate[g] = sum + b_ih[g * 512 + d3] + b_hh[g * 512 + d3];
                }
                int ci = b2 * 512 + d3;
                float cn = sigf(gate[1]) * cbuf[ci] + sigf(gate[0]) * tanhf(gate[2]);
                cbuf[ci] = cn;
                float hn = sigf(gate[3]) * tanhf(cn);
                hbuf[ci] = hn;
                hhist[(t * 8 + b2) * 512 + d3] = hn;
            }
        }
        gridSync(++bt);
    }

    // ========== G: all predictions in one GEMM: out[96][20000] = h_hist @ W_fc^T ==========
    // block = (row-half hr, v-group of 160); H-half (48x512=96KB) staged in LDS;
    // per wave: 2 batches of 10 v, register tile 10v x 6rows, lanes = (r8, d8)
    {
        int hr = bid & 1, vg = bid >> 1;
        if (vg < 125) {
            float4* hs4 = (float4*)smemf;   // [48][128]
            const float4* hh4 = (const float4*)hhist + hr * 6144;
            #pragma unroll
            for (int i = 0; i < 12; i++) hs4[tid + i * 512] = hh4[tid + i * 512];
            __syncthreads();
            int r8 = lane >> 3, d8 = lane & 7;
            int v0 = vg * 160;
            #pragma unroll
            for (int bi = 0; bi < 2; bi++) {
                int vb = v0 + (bw * 2 + bi) * 10;
                float acc[10][6];
                #pragma unroll
                for (int vv = 0; vv < 10; vv++)
                    #pragma unroll
                    for (int rr = 0; rr < 6; rr++) acc[vv][rr] = 0.0f;
                for (int i = 0; i < 16; i++) {
                    float4 h6[6];
                    #pragma unroll
                    for (int rr = 0; rr < 6; rr++) h6[rr] = hs4[(r8 * 6 + rr) * 128 + i * 8 + d8];
                    #pragma unroll
                    for (int vv = 0; vv < 10; vv++) {
                        float4 w = ((const float4*)W_fc)[(size_t)(vb + vv) * 128 + i * 8 + d8];
                        #pragma unroll
                        for (int rr = 0; rr < 6; rr++) {
                            acc[vv][rr] = fmaf(w.x, h6[rr].x, acc[vv][rr]);
                            acc[vv][rr] = fmaf(w.y, h6[rr].y, acc[vv][rr]);
                            acc[vv][rr] = fmaf(w.z, h6[rr].z, acc[vv][rr]);
                            acc[vv][rr] = fmaf(w.w, h6[rr].w, acc[vv][rr]);
                        }
                    }
                }
                #pragma unroll
                for (int vv = 0; vv < 10; vv++) {
                    #pragma unroll
                    for (int rr = 0; rr < 6; rr++) {
                        float a = acc[vv][rr];
                        a += __shfl_xor(a, 1);
                        a += __shfl_xor(a, 2);
                        a += __shfl_xor(a, 4);
                        if (d8 == 0) {
                            int row = hr * 48 + r8 * 6 + rr;   // row = t*8 + b
                            int tt = row >> 3, b2 = row & 7;
                            out[((size_t)b2 * Tz + tt) * Vz + vb + vv] = a + b_fc[vb + vv];
                        }
                    }
                }
            }
        }
    }
}

extern "C" void kernel_launch(void* const* d_in, const int* in_sizes, int n_in,
                              void* d_out, int out_size, void* d_ws, size_t ws_size,
                              hipStream_t stream) {
    const float* enc      = (const float*)d_in[0];
    const int*   caps     = (const int*)d_in[1];
    const int*   caplen   = (const int*)d_in[2];
    const float* W_c      = (const float*)d_in[3];
    const float* W_hc     = (const float*)d_in[4];
    const float* W_i_hat  = (const float*)d_in[5];
    const float* b_c      = (const float*)d_in[6];
    const float* W_s      = (const float*)d_in[8];
    const float* W_hs     = (const float*)d_in[9];
    const float* W_i      = (const float*)d_in[10];
    const float* b_s      = (const float*)d_in[11];
    const float* emb      = (const float*)d_in[13];
    const float* W_ih     = (const float*)d_in[14];
    const float* W_hh     = (const float*)d_in[15];
    const float* b_ih     = (const float*)d_in[16];
    const float* b_hh     = (const float*)d_in[17];
    const float* W_init_h = (const float*)d_in[18];
    const float* b_init_h = (const float*)d_in[19];
    const float* W_init_c = (const float*)d_in[20];
    const float* b_init_c = (const float*)d_in[21];
    const float* W_fc     = (const float*)d_in[22];
    const float* b_fc     = (const float*)d_in[23];

    k_main<<<dim3(NB), dim3(NT), 0, stream>>>(
        enc, caps, caplen, W_c, b_c, W_i_hat, W_s, b_s, W_i, emb,
        W_ih, W_hh, b_ih, b_hh, W_init_h, b_init_h, W_init_c, b_init_c,
        W_hc, W_hs, W_fc, b_fc, (float*)d_out, (float*)d_ws);
}

// Round 2
// 2377.955 us; speedup vs baseline: 2.2890x; 2.2890x over previous
//
#include <hip/hip_runtime.h>

#define Bz 8
#define T1z 13
#define Tz 12
#define Vz 20000
#define Ez 512
#define Dz 512
#define Kz 512
#define Cz 2048
#define Pz 64
#define NB 256
#define NT 512

// ---- persistent-kernel grid barrier state (device globals persist across graph replays;
//      sense is a monotone generation counter so no reset is needed) ----
__device__ unsigned g_slots[NB];
__device__ unsigned g_gen2;

__device__ __forceinline__ float waveReduce(float v) {
    #pragma unroll
    for (int off = 32; off > 0; off >>= 1) v += __shfl_xor(v, off);
    return v;
}

__device__ __forceinline__ float sigf(float x) { return 1.0f / (1.0f + expf(-x)); }

// Grid-wide barrier, coherence-cost-minimized:
//  * arrival: ONE release store (s_waitcnt + buffer_wbl2 once — flushes this block's
//    dirty L2 lines to the device coherence point)
//  * spin: RELAXED agent loads only — scope-coherent but NO buffer_inv per poll.
//    (Round-1 version used ACQUIRE polls: each emitted an L1+L2 invalidate; 255 blocks
//    spinning = invalidate storm = ~70 us/barrier and all caches wiped every phase.)
//  * exit: ONE acquire load (single buffer_inv) so subsequent normal loads see fresh data.
__device__ __forceinline__ void gridSync(unsigned target) {
    __syncthreads();
    if (threadIdx.x == 0) {
        __hip_atomic_store(&g_slots[blockIdx.x], target, __ATOMIC_RELEASE, __HIP_MEMORY_SCOPE_AGENT);
    }
    if (blockIdx.x == 0) {
        if (threadIdx.x < 64) {
            long guard = 0;
            for (;;) {
                bool ok = true;
                #pragma unroll
                for (int i = 0; i < 4; i++) {
                    unsigned v = __hip_atomic_load(&g_slots[threadIdx.x + i * 64],
                                                   __ATOMIC_RELAXED, __HIP_MEMORY_SCOPE_AGENT);
                    ok = ok && ((int)(v - target) >= 0);
                }
                if (__all(ok)) break;
                __builtin_amdgcn_s_sleep(2);
                if (++guard > (1L << 20)) break;
            }
            if (threadIdx.x == 0) {
                __hip_atomic_store(&g_gen2, target, __ATOMIC_RELEASE, __HIP_MEMORY_SCOPE_AGENT);
            }
        }
    } else if (threadIdx.x == 0) {
        long guard = 0;
        while ((int)(__hip_atomic_load(&g_gen2, __ATOMIC_RELAXED, __HIP_MEMORY_SCOPE_AGENT) - target) < 0) {
            __builtin_amdgcn_s_sleep(2);
            if (++guard > (1L << 20)) break;
        }
    }
    if (threadIdx.x == 0) {
        (void)__hip_atomic_load(&g_gen2, __ATOMIC_ACQUIRE, __HIP_MEMORY_SCOPE_AGENT);
    }
    __syncthreads();
}

__global__ __launch_bounds__(NT, 2) void k_main(
    const float* __restrict__ enc, const int* __restrict__ caps, const int* __restrict__ caplen,
    const float* __restrict__ W_c, const float* __restrict__ b_c, const float* __restrict__ W_i_hat,
    const float* __restrict__ W_s, const float* __restrict__ b_s, const float* __restrict__ W_i,
    const float* __restrict__ emb,
    const float* __restrict__ W_ih, const float* __restrict__ W_hh,
    const float* __restrict__ b_ih, const float* __restrict__ b_hh,
    const float* __restrict__ W_init_h, const float* __restrict__ b_init_h,
    const float* __restrict__ W_init_c, const float* __restrict__ b_init_c,
    const float* __restrict__ W_hc, const float* __restrict__ W_hs,
    const float* __restrict__ W_fc, const float* __restrict__ b_fc,
    float* __restrict__ out, float* __restrict__ ws)
{
    // 24832 floats = 99,328 B of LDS (one block per CU; max gfx950 WG LDS is 160 KiB)
    __shared__ __align__(16) float smemf[24832];

    float* vmean  = ws;                     // 16384
    float* hbuf   = vmean + 16384;          // 4096
    float* cbuf   = hbuf + 4096;            // 4096
    float* qpart  = cbuf + 4096;            // 4ch*2which*8b*512k = 32768
    float* beta   = qpart + 32768;          // 16384
    float* scoreS = beta + 16384;           // 512  [b][p]
    float* xcat   = scoreS + 512;           // 8*3072 = 24576
    float* hhist  = xcat + 24576;           // 96*512 = 49152
    float* spart  = hhist + 49152;          // 32*8*64*512 = 8388608

    const int tid  = threadIdx.x;
    const int bid  = blockIdx.x;
    const int lane = tid & 63;
    const int bw   = tid >> 6;              // wave in block: 0..7
    const int gw   = bid * 8 + bw;          // global wave: 0..2047

    unsigned bt = __hip_atomic_load(&g_gen2, __ATOMIC_RELAXED, __HIP_MEMORY_SCOPE_AGENT);

    // ================= phase 0: tail fills + Vmean =================
    {
        int gid = bid * NT + tid;
        const int base = Bz * Tz * Vz;
        const int nCap = Bz * T1z;          // 104
        const int nAlp = Bz * Tz * Pz;      // 6144
        if (gid < nCap + Bz + nAlp + Bz) {
            if (gid < nCap) out[base + gid] = (float)caps[gid];
            else if (gid < nCap + Bz) out[base + gid] = (float)(caplen[gid - nCap] - 1);
            else if (gid < nCap + Bz + nAlp) out[base + gid] = 0.0f;
            else out[base + gid] = (float)(gid - (nCap + Bz + nAlp));
        }
        #pragma unroll
        for (int j = 0; j < 8; j++) {
            int w = gw * 8 + j;             // (b*Cz + c), 0..16383
            float v = enc[(size_t)w * 64 + lane];
            v = waveReduce(v);
            if (lane == 0) vmean[w] = v * (1.0f / 64.0f);
        }
    }
    gridSync(++bt);

    // ================= phase 1: h0 / c0 =================
    {
        #pragma unroll
        for (int j = 0; j < 4; j++) {
            int o = gw * 4 + j;             // 0..8191
            int which = o >> 12;
            int rem = o & 4095;
            int b = rem >> 9, d = rem & 511;
            const float* W = which ? W_init_c : W_init_h;
            float acc = 0.0f;
            #pragma unroll 4
            for (int i = 0; i < 32; i++) {
                int cc = i * 64 + lane;
                acc = fmaf(vmean[b * Cz + cc], W[(size_t)d * Cz + cc], acc);
            }
            acc = waveReduce(acc);
            if (lane == 0) {
                if (which) cbuf[rem] = acc + b_init_c[d];
                else       hbuf[rem] = acc + b_init_h[d];
            }
        }
    }
    gridSync(++bt);

    for (int t = 0; t < Tz; t++) {
        // ========== A: q projections (h@W_hc, h@W_hs; d-split 4) + zero scoreS ==========
        {
            int gid = bid * NT + tid;
            if (gid < 32768) {
                int k = gid & 511;
                int r = gid >> 9;           // 0..63
                int b = r & 7, which = (r >> 3) & 1, ch = r >> 4;
                const float* W = which ? W_hs : W_hc;
                const float* hb = hbuf + b * Dz;
                float acc = 0.0f;
                int d0 = ch * 128;
                #pragma unroll 8
                for (int d = d0; d < d0 + 128; d++) acc = fmaf(hb[d], W[(size_t)d * Kz + k], acc);
                qpart[(size_t)r * Kz + k] = acc;
            } else if (gid < 32768 + 512) {
                scoreS[gid - 32768] = 0.0f;
            }
        }
        gridSync(++bt);

        // ========== B: channel attention scores + batch softmax -> beta ==========
        // block handles c in [bid*8, bid*8+8); wave bw == batch b; q cached in regs
        {
            float* sL = smemf;              // [8 c][8 b]
            int b = bw;
            const float4* qp4 = (const float4*)qpart;
            const float4* wc4 = (const float4*)W_c;
            const float4* bc4 = (const float4*)b_c;
            const float4* wi4 = (const float4*)W_i_hat;
            int k0 = lane, k1 = 64 + lane;
            float4 q0 = bc4[k0], q1 = bc4[k1];
            #pragma unroll
            for (int ch = 0; ch < 4; ch++) {
                float4 a = qp4[((ch * 2) * Bz + b) * 128 + k0];
                float4 e = qp4[((ch * 2) * Bz + b) * 128 + k1];
                q0.x += a.x; q0.y += a.y; q0.z += a.z; q0.w += a.w;
                q1.x += e.x; q1.y += e.y; q1.z += e.z; q1.w += e.w;
            }
            float4 wcA = wc4[k0], wcB = wc4[k1];
            float4 wiA = wi4[k0], wiB = wi4[k1];
            #pragma unroll
            for (int j = 0; j < 8; j++) {
                int cc = bid * 8 + j;
                float v = vmean[b * Cz + cc];
                float acc = 0.0f;
                acc += tanhf(fmaf(v, wcA.x, q0.x)) * wiA.x;
                acc += tanhf(fmaf(v, wcA.y, q0.y)) * wiA.y;
                acc += tanhf(fmaf(v, wcA.z, q0.z)) * wiA.z;
                acc += tanhf(fmaf(v, wcA.w, q0.w)) * wiA.w;
                acc += tanhf(fmaf(v, wcB.x, q1.x)) * wiB.x;
                acc += tanhf(fmaf(v, wcB.y, q1.y)) * wiB.y;
                acc += tanhf(fmaf(v, wcB.z, q1.z)) * wiB.z;
                acc += tanhf(fmaf(v, wcB.w, q1.w)) * wiB.w;
                acc = waveReduce(acc);
                if (lane == 0) sL[j * 8 + b] = acc;
            }
            __syncthreads();
            if (tid < 64) {
                int j = tid >> 3, b2 = tid & 7;
                float m = -1e30f;
                #pragma unroll
                for (int q = 0; q < 8; q++) m = fmaxf(m, sL[j * 8 + q]);
                float s = 0.0f;
                #pragma unroll
                for (int q = 0; q < 8; q++) s += expf(sL[j * 8 + q] - m);
                beta[b2 * Cz + bid * 8 + j] = expf(sL[j * 8 + b2] - m) / s;
            }
        }
        gridSync(++bt);

        // ========== C: partial einsum spart[sl][b][p][k] = sum_{c in slice} enc*beta*W_s ==========
        // block = (slice 0..31, b 0..7); 64p x 512k tile; 8x8 per-thread register tile
        {
            float* As = smemf;              // [32][64]  (c x p, pre-scaled by beta)
            float* Bs = smemf + 2048;       // [32][512] (c x k)
            int b = bid & 7, sl = bid >> 3;
            int kq = tid & 63, pq = tid >> 6;
            float acc[8][8];
            #pragma unroll
            for (int i = 0; i < 8; i++)
                #pragma unroll
                for (int j = 0; j < 8; j++) acc[i][j] = 0.0f;

            #pragma unroll
            for (int half = 0; half < 2; half++) {
                int c0 = sl * 64 + half * 32;
                {   // stage As: 2048 floats, 1 float4/thread
                    int cl = tid >> 4, p4 = tid & 15;
                    int cc = c0 + cl;
                    float btv = beta[b * Cz + cc];
                    float4 ev = ((const float4*)enc)[(size_t)(b * Cz + cc) * 16 + p4];
                    ((float4*)As)[cl * 16 + p4] = make_float4(ev.x * btv, ev.y * btv, ev.z * btv, ev.w * btv);
                }
                {   // stage Bs: 16384 floats, 8 float4/thread (128B segments)
                    int base4 = tid * 8;
                    int cl = base4 >> 7, kf = base4 & 127;
                    const float4* wsrc = (const float4*)(W_s + (size_t)(c0 + cl) * Kz);
                    float4* bdst = (float4*)Bs + cl * 128 + kf;
                    #pragma unroll
                    for (int j = 0; j < 8; j++) bdst[j] = wsrc[kf + j];
                }
                __syncthreads();
                #pragma unroll 4
                for (int cc = 0; cc < 32; cc++) {
                    float4 a0 = ((float4*)As)[cc * 16 + pq * 2];
                    float4 a1 = ((float4*)As)[cc * 16 + pq * 2 + 1];
                    float4 b0 = ((float4*)Bs)[cc * 128 + kq * 2];
                    float4 b1 = ((float4*)Bs)[cc * 128 + kq * 2 + 1];
                    float av[8] = {a0.x, a0.y, a0.z, a0.w, a1.x, a1.y, a1.z, a1.w};
                    float bv[8] = {b0.x, b0.y, b0.z, b0.w, b1.x, b1.y, b1.z, b1.w};
                    #pragma unroll
                    for (int i = 0; i < 8; i++)
                        #pragma unroll
                        for (int j = 0; j < 8; j++)
                            acc[i][j] = fmaf(av[i], bv[j], acc[i][j]);
                }
                __syncthreads();
            }
            float* dst = spart + (size_t)(sl * 8 + b) * 64 * 512;
            #pragma unroll
            for (int r = 0; r < 8; r++) {
                int p = pq * 8 + r;
                float4* dp = (float4*)(dst + (size_t)p * 512 + kq * 8);
                dp[0] = make_float4(acc[r][0], acc[r][1], acc[r][2], acc[r][3]);
                dp[1] = make_float4(acc[r][4], acc[r][5], acc[r][6], acc[r][7]);
            }
        }
        gridSync(++bt);

        // ========== D: spatial scores (k-split over blocks, atomicAdd into scoreS) ==========
        // block = (p 0..63, k-quarter 0..3); wave bw == b; lanes: 32 k-float4 x 2 slice-halves
        {
            int p = bid >> 2, kqr = bid & 3;
            int b = bw;
            int kf = lane & 31;
            int sh = lane >> 5;
            int kg = kqr * 32 + kf;         // global float4 index 0..127
            const float4* sp4 = (const float4*)spart;
            float sx = 0.f, sy = 0.f, sz = 0.f, sw = 0.f;
            #pragma unroll
            for (int i = 0; i < 16; i++) {
                int sl = sh * 16 + i;
                float4 tv = sp4[((size_t)(sl * 8 + b) * 64 + p) * 128 + kg];
                sx += tv.x; sy += tv.y; sz += tv.z; sw += tv.w;
            }
            sx += __shfl_xor(sx, 32); sy += __shfl_xor(sy, 32);
            sz += __shfl_xor(sz, 32); sw += __shfl_xor(sw, 32);
            float acc = 0.0f;
            if (sh == 0) {
                float4 q = ((const float4*)b_s)[kg];
                #pragma unroll
                for (int ch = 0; ch < 4; ch++) {
                    float4 tq = ((const float4*)qpart)[((ch * 2 + 1) * Bz + b) * 128 + kg];
                    q.x += tq.x; q.y += tq.y; q.z += tq.z; q.w += tq.w;
                }
                float4 wi = ((const float4*)W_i)[kg];
                acc = tanhf(sx + q.x) * wi.x + tanhf(sy + q.y) * wi.y +
                      tanhf(sz + q.z) * wi.z + tanhf(sw + q.w) * wi.w;
            }
            acc = waveReduce(acc);
            if (lane == 0) atomicAdd(&scoreS[b * 64 + p], acc);
        }
        gridSync(++bt);

        // ========== E: alpha softmax (per-wave, in-reg) + awe -> xcat; emb/h segments ==========
        {
            int b = gw >> 8;                // 8 b x 256 waves
            int cg = gw & 255;
            float sc[8];
            #pragma unroll
            for (int bb = 0; bb < 8; bb++) sc[bb] = scoreS[bb * 64 + lane];
            float m = -1e30f;
            #pragma unroll
            for (int bb = 0; bb < 8; bb++) m = fmaxf(m, sc[bb]);
            float denom = 0.0f;
            #pragma unroll
            for (int bb = 0; bb < 8; bb++) denom += expf(sc[bb] - m);
            float aval = expf(sc[b] - m) / denom;   // alpha[b][p=lane]
            #pragma unroll
            for (int j = 0; j < 8; j++) {
                int cc = cg * 8 + j;
                float e = enc[(size_t)(b * Cz + cc) * 64 + lane];
                float v = waveReduce(e * aval);
                if (lane == 0) xcat[b * 3072 + Ez + cc] = beta[b * Cz + cc] * v * (1.0f / 64.0f);
            }
            int gid = bid * NT + tid;
            if (gid < 8192) {
                int b2 = gid >> 10, r = gid & 1023;
                if (r < Ez) xcat[b2 * 3072 + r] = emb[(size_t)caps[b2 * T1z + t] * Ez + r];
                else        xcat[b2 * 3072 + 2560 + (r - Ez)] = hbuf[b2 * Dz + (r - Ez)];
            }
        }
        gridSync(++bt);

        // ========== F: gates (full 3072 contraction) + LSTM cell, fused ==========
        // block = d-pair (bid*2, bid*2+1); wave = (e-quarter q, dd); each wave does 4 gate rows
        {
            float* sx = smemf;              // xcat staged: 24576 floats
            float* gp = smemf + 24576;      // partials: [bw][g][b] = 8*4*8
            float4* sx4 = (float4*)sx;
            const float4* xc4 = (const float4*)xcat;
            #pragma unroll
            for (int i = 0; i < 12; i++) sx4[tid + i * 512] = xc4[tid + i * 512];
            __syncthreads();
            int q = bw >> 1, dd = bw & 1;
            int d2 = bid * 2 + dd;
            int b = lane >> 3, e8 = lane & 7;
            float accg[4] = {0.f, 0.f, 0.f, 0.f};
            #pragma unroll 4
            for (int i = 0; i < 24; i++) {
                int ef4 = q * 192 + i * 8 + e8;     // float4 index into 768-f4 row
                float4 xv = sx4[b * 768 + ef4];
                bool ih = (ef4 < 640);              // wave-uniform per i
                #pragma unroll
                for (int g = 0; g < 4; g++) {
                    int j = g * 512 + d2;
                    float4 w = ih ? ((const float4*)W_ih)[(size_t)j * 640 + ef4]
                                  : ((const float4*)W_hh)[(size_t)j * 128 + (ef4 - 640)];
                    accg[g] = fmaf(xv.x, w.x, accg[g]);
                    accg[g] = fmaf(xv.y, w.y, accg[g]);
                    accg[g] = fmaf(xv.z, w.z, accg[g]);
                    accg[g] = fmaf(xv.w, w.w, accg[g]);
                }
            }
            #pragma unroll
            for (int mm = 1; mm < 8; mm <<= 1) {
                #pragma unroll
                for (int g = 0; g < 4; g++) accg[g] += __shfl_xor(accg[g], mm);
            }
            if (e8 == 0) {
                #pragma unroll
                for (int g = 0; g < 4; g++) gp[(bw * 4 + g) * 8 + b] = accg[g];
            }
            __syncthreads();
            if (tid < 16) {
                int b2 = tid & 7, ddd = tid >> 3;
                int d3 = bid * 2 + ddd;
                float gate[4];
                #pragma unroll
                for (int g = 0; g < 4; g++) {
                    float sum = 0.0f;
                    #pragma unroll
                    for (int qq = 0; qq < 4; qq++) sum += gp[((qq * 2 + ddd) * 4 + g) * 8 + b2];
                    gate[g] = sum + b_ih[g * 512 + d3] + b_hh[g * 512 + d3];
                }
                int ci = b2 * 512 + d3;
                float cn = sigf(gate[1]) * cbuf[ci] + sigf(gate[0]) * tanhf(gate[2]);
                cbuf[ci] = cn;
                float hn = sigf(gate[3]) * tanhf(cn);
                hbuf[ci] = hn;
                hhist[(t * 8 + b2) * 512 + d3] = hn;
            }
        }
        gridSync(++bt);
    }

    // ========== G: all predictions in one GEMM: out[96][20000] = h_hist @ W_fc^T ==========
    // block = (row-half hr, v-group of 160); H-half (48x512=96KB) staged in LDS;
    // per wave: 2 batches of 10 v, register tile 10v x 6rows, lanes = (r8, d8)
    {
        int hr = bid & 1, vg = bid >> 1;
        if (vg < 125) {
            float4* hs4 = (float4*)smemf;   // [48][128]
            const float4* hh4 = (const float4*)hhist + hr * 6144;
            #pragma unroll
            for (int i = 0; i < 12; i++) hs4[tid + i * 512] = hh4[tid + i * 512];
            __syncthreads();
            int r8 = lane >> 3, d8 = lane & 7;
            int v0 = vg * 160;
            #pragma unroll
            for (int bi = 0; bi < 2; bi++) {
                int vb = v0 + (bw * 2 + bi) * 10;
                float acc[10][6];
                #pragma unroll
                for (int vv = 0; vv < 10; vv++)
                    #pragma unroll
                    for (int rr = 0; rr < 6; rr++) acc[vv][rr] = 0.0f;
                for (int i = 0; i < 16; i++) {
                    float4 h6[6];
                    #pragma unroll
                    for (int rr = 0; rr < 6; rr++) h6[rr] = hs4[(r8 * 6 + rr) * 128 + i * 8 + d8];
                    #pragma unroll
                    for (int vv = 0; vv < 10; vv++) {
                        float4 w = ((const float4*)W_fc)[(size_t)(vb + vv) * 128 + i * 8 + d8];
                        #pragma unroll
                        for (int rr = 0; rr < 6; rr++) {
                            acc[vv][rr] = fmaf(w.x, h6[rr].x, acc[vv][rr]);
                            acc[vv][rr] = fmaf(w.y, h6[rr].y, acc[vv][rr]);
                            acc[vv][rr] = fmaf(w.z, h6[rr].z, acc[vv][rr]);
                            acc[vv][rr] = fmaf(w.w, h6[rr].w, acc[vv][rr]);
                        }
                    }
                }
                #pragma unroll
                for (int vv = 0; vv < 10; vv++) {
                    #pragma unroll
                    for (int rr = 0; rr < 6; rr++) {
                        float a = acc[vv][rr];
                        a += __shfl_xor(a, 1);
                        a += __shfl_xor(a, 2);
                        a += __shfl_xor(a, 4);
                        if (d8 == 0) {
                            int row = hr * 48 + r8 * 6 + rr;   // row = t*8 + b
                            int tt = row >> 3, b2 = row & 7;
                            out[((size_t)b2 * Tz + tt) * Vz + vb + vv] = a + b_fc[vb + vv];
                        }
                    }
                }
            }
        }
    }
}

extern "C" void kernel_launch(void* const* d_in, const int* in_sizes, int n_in,
                              void* d_out, int out_size, void* d_ws, size_t ws_size,
                              hipStream_t stream) {
    const float* enc      = (const float*)d_in[0];
    const int*   caps     = (const int*)d_in[1];
    const int*   caplen   = (const int*)d_in[2];
    const float* W_c      = (const float*)d_in[3];
    const float* W_hc     = (const float*)d_in[4];
    const float* W_i_hat  = (const float*)d_in[5];
    const float* b_c      = (const float*)d_in[6];
    const float* W_s      = (const float*)d_in[8];
    const float* W_hs     = (const float*)d_in[9];
    const float* W_i      = (const float*)d_in[10];
    const float* b_s      = (const float*)d_in[11];
    const float* emb      = (const float*)d_in[13];
    const float* W_ih     = (const float*)d_in[14];
    const float* W_hh     = (const float*)d_in[15];
    const float* b_ih     = (const float*)d_in[16];
    const float* b_hh     = (const float*)d_in[17];
    const float* W_init_h = (const float*)d_in[18];
    const float* b_init_h = (const float*)d_in[19];
    const float* W_init_c = (const float*)d_in[20];
    const float* b_init_c = (const float*)d_in[21];
    const float* W_fc     = (const float*)d_in[22];
    const float* b_fc     = (const float*)d_in[23];

    k_main<<<dim3(NB), dim3(NT), 0, stream>>>(
        enc, caps, caplen, W_c, b_c, W_i_hat, W_s, b_s, W_i, emb,
        W_ih, W_hh, b_ih, b_hh, W_init_h, b_init_h, W_init_c, b_init_c,
        W_hc, W_hs, W_fc, b_fc, (float*)d_out, (float*)d_ws);
}

// Round 3
// 1428.331 us; speedup vs baseline: 3.8109x; 1.6648x over previous
//
#include <hip/hip_runtime.h>

#define Bz 8
#define T1z 13
#define Tz 12
#define Vz 20000
#define Ez 512
#define Dz 512
#define Kz 512
#define Cz 2048
#define Pz 64
#define NB 256
#define NT 512

// ---- persistent-kernel grid barrier state (monotone generation counter) ----
__device__ unsigned g_slots[NB];
__device__ unsigned g_gen2;

__device__ __forceinline__ float waveReduce(float v) {
    #pragma unroll
    for (int off = 32; off > 0; off >>= 1) v += __shfl_xor(v, off);
    return v;
}

__device__ __forceinline__ float sigf(float x) { return 1.0f / (1.0f + expf(-x)); }

// Grid-wide barrier: RELAXED polls (no per-poll buffer_inv), one RELEASE at arrival,
// one ACQUIRE at exit. Guard valves bound the spin.
__device__ __forceinline__ void gridSync(unsigned target) {
    __syncthreads();
    if (threadIdx.x == 0) {
        __hip_atomic_store(&g_slots[blockIdx.x], target, __ATOMIC_RELEASE, __HIP_MEMORY_SCOPE_AGENT);
    }
    if (blockIdx.x == 0) {
        if (threadIdx.x < 64) {
            long guard = 0;
            for (;;) {
                bool ok = true;
                #pragma unroll
                for (int i = 0; i < 4; i++) {
                    unsigned v = __hip_atomic_load(&g_slots[threadIdx.x + i * 64],
                                                   __ATOMIC_RELAXED, __HIP_MEMORY_SCOPE_AGENT);
                    ok = ok && ((int)(v - target) >= 0);
                }
                if (__all(ok)) break;
                __builtin_amdgcn_s_sleep(2);
                if (++guard > (1L << 20)) break;
            }
            if (threadIdx.x == 0) {
                __hip_atomic_store(&g_gen2, target, __ATOMIC_RELEASE, __HIP_MEMORY_SCOPE_AGENT);
            }
        }
    } else if (threadIdx.x == 0) {
        long guard = 0;
        while ((int)(__hip_atomic_load(&g_gen2, __ATOMIC_RELAXED, __HIP_MEMORY_SCOPE_AGENT) - target) < 0) {
            __builtin_amdgcn_s_sleep(2);
            if (++guard > (1L << 20)) break;
        }
    }
    if (threadIdx.x == 0) {
        (void)__hip_atomic_load(&g_gen2, __ATOMIC_ACQUIRE, __HIP_MEMORY_SCOPE_AGENT);
    }
    __syncthreads();
}

// LDS layout (floats): [0..6143] scratch (C: As 2048 + Bs 4096; B: sL; F: gp)
//                      [6144..8319] WA (A-phase weight slab, 128x17 padded)
//                      [8320..32895] WF (F-phase W_ih/W_hh rows, 8 x 768 float4)
// Total 32896 floats = 131,584 B (< 160 KiB, 1 block/CU). G aliases [0..24575].
#define S_AS 0
#define S_BS 2048
#define S_WA 6144
#define S_WF 8320

__global__ __launch_bounds__(NT, 2) void k_main(
    const float* __restrict__ enc, const int* __restrict__ caps, const int* __restrict__ caplen,
    const float* __restrict__ W_c, const float* __restrict__ b_c, const float* __restrict__ W_i_hat,
    const float* __restrict__ W_s, const float* __restrict__ b_s, const float* __restrict__ W_i,
    const float* __restrict__ emb,
    const float* __restrict__ W_ih, const float* __restrict__ W_hh,
    const float* __restrict__ b_ih, const float* __restrict__ b_hh,
    const float* __restrict__ W_init_h, const float* __restrict__ b_init_h,
    const float* __restrict__ W_init_c, const float* __restrict__ b_init_c,
    const float* __restrict__ W_hc, const float* __restrict__ W_hs,
    const float* __restrict__ W_fc, const float* __restrict__ b_fc,
    float* __restrict__ out, float* __restrict__ ws)
{
    __shared__ __align__(16) float smem[32896];

    float* vmean  = ws;                     // 16384
    float* hbuf   = vmean + 16384;          // 4096
    float* cbuf   = hbuf + 4096;            // 4096
    float* qpart  = cbuf + 4096;            // 4ch*2which*8b*512k = 32768
    float* beta   = qpart + 32768;          // 16384
    float* scoreS = beta + 16384;           // 512  [b][p]
    float* xcat   = scoreS + 512;           // 8*3072 = 24576
    float* hhist  = xcat + 24576;           // 96*512 = 49152
    float* spart  = hhist + 49152;          // 8ch*8b*64p*512k = 2097152 (8.4 MB)

    const int tid  = threadIdx.x;
    const int bid  = blockIdx.x;
    const int lane = tid & 63;
    const int bw   = tid >> 6;              // wave in block: 0..7
    const int gw   = bid * 8 + bw;          // global wave: 0..2047

    unsigned bt = __hip_atomic_load(&g_gen2, __ATOMIC_RELAXED, __HIP_MEMORY_SCOPE_AGENT);

    // ---- A-phase decomposition for this block: (which, chunkA, ksub) ----
    const int whichA = bid >> 7;            // 0: W_hc, 1: W_hs
    const int chunkA = (bid >> 5) & 3;      // d-chunk of 128
    const int ksubA  = bid & 31;            // k-slab of 16

    // ---- C-phase decomposition: XCD-aware (xcd = bid&7 under round-robin dispatch).
    // b-pairs and ktile-pairs colocated per XCD: W_s slab fetched by <=2 XCDs,
    // enc slab by <=2 XCDs (minimizes L2-fill duplication; 4x8x8 sharing groups / 8 XCDs).
    const int xcdC   = bid & 7;
    const int innC   = bid >> 3;
    const int chunkC = ((innC & 3) << 1) | (xcdC & 1);        // 0..7 (256 c each)
    const int ktileC = (((innC >> 2) & 1) << 1) | ((xcdC >> 1) & 1); // 0..3 (128 k each)
    const int bC     = ((innC >> 3) << 1) | ((xcdC >> 2) & 1);       // 0..7

    // ================= one-time LDS weight staging =================
    {
        // WF: this block's 8 LSTM rows (4 gates x d-pair), 8 x 768 float4
        float4* wf4 = (float4*)(smem + S_WF);
        const float4* wih4 = (const float4*)W_ih;   // row = 640 f4
        const float4* whh4 = (const float4*)W_hh;   // row = 128 f4
        #pragma unroll
        for (int i = 0; i < 12; i++) {
            int f4i = i * 512 + tid;                // 0..6143
            int r2  = f4i / 768;                    // 0..7 = g*2+dd
            int col = f4i - r2 * 768;
            int j   = (r2 >> 1) * 512 + bid * 2 + (r2 & 1);
            wf4[r2 * 768 + col] = (col < 640) ? wih4[(size_t)j * 640 + col]
                                              : whh4[(size_t)j * 128 + (col - 640)];
        }
        // WA: W_{hc|hs}[chunkA*128 .. +128][ksubA*16 .. +16], padded [128][17]
        const float* Wsel = whichA ? W_hs : W_hc;
        #pragma unroll
        for (int i = 0; i < 4; i++) {
            int e = i * 512 + tid;                  // 0..2047
            int d = e >> 4, kk = e & 15;
            smem[S_WA + d * 17 + kk] = Wsel[(size_t)(chunkA * 128 + d) * Kz + ksubA * 16 + kk];
        }
    }

    // ================= phase 0: tail fills + Vmean =================
    {
        int gid = bid * NT + tid;
        const int base = Bz * Tz * Vz;
        const int nCap = Bz * T1z;
        const int nAlp = Bz * Tz * Pz;
        if (gid < nCap + Bz + nAlp + Bz) {
            if (gid < nCap) out[base + gid] = (float)caps[gid];
            else if (gid < nCap + Bz) out[base + gid] = (float)(caplen[gid - nCap] - 1);
            else if (gid < nCap + Bz + nAlp) out[base + gid] = 0.0f;
            else out[base + gid] = (float)(gid - (nCap + Bz + nAlp));
        }
        #pragma unroll
        for (int j = 0; j < 8; j++) {
            int w = gw * 8 + j;
            float v = enc[(size_t)w * 64 + lane];
            v = waveReduce(v);
            if (lane == 0) vmean[w] = v * (1.0f / 64.0f);
        }
    }
    gridSync(++bt);

    // ================= phase 1: h0 / c0 =================
    {
        #pragma unroll
        for (int j = 0; j < 4; j++) {
            int o = gw * 4 + j;
            int which = o >> 12;
            int rem = o & 4095;
            int b = rem >> 9, d = rem & 511;
            const float* W = which ? W_init_c : W_init_h;
            float acc = 0.0f;
            #pragma unroll 4
            for (int i = 0; i < 32; i++) {
                int cc = i * 64 + lane;
                acc = fmaf(vmean[b * Cz + cc], W[(size_t)d * Cz + cc], acc);
            }
            acc = waveReduce(acc);
            if (lane == 0) {
                if (which) cbuf[rem] = acc + b_init_c[d];
                else       hbuf[rem] = acc + b_init_h[d];
            }
        }
    }
    gridSync(++bt);

    for (int t = 0; t < Tz; t++) {
        // ========== A: q projections from LDS-cached W slabs + zero scoreS ==========
        // thread: out = tid>>2 -> (b = out>>4 == bw, kk = out&15), dq = tid&3 (d-mod-4 split)
        {
            int kk = (tid >> 2) & 15;
            int dq = tid & 3;
            const float* hb = hbuf + bw * Dz + chunkA * 128;
            float acc = 0.0f;
            #pragma unroll 8
            for (int j = 0; j < 32; j++) {
                int d = j * 4 + dq;
                acc = fmaf(hb[d], smem[S_WA + d * 17 + kk], acc);
            }
            acc += __shfl_xor(acc, 1);
            acc += __shfl_xor(acc, 2);
            if (dq == 0)
                qpart[(size_t)((chunkA * 2 + whichA) * Bz + bw) * Kz + ksubA * 16 + kk] = acc;
            if (bid == 255) scoreS[tid] = 0.0f;
        }
        gridSync(++bt);

        // ========== B: channel attention scores + batch softmax -> beta ==========
        {
            float* sL = smem;               // [8 c][8 b]
            int b = bw;
            const float4* qp4 = (const float4*)qpart;
            const float4* wc4 = (const float4*)W_c;
            const float4* bc4 = (const float4*)b_c;
            const float4* wi4 = (const float4*)W_i_hat;
            int k0 = lane, k1 = 64 + lane;
            float4 q0 = bc4[k0], q1 = bc4[k1];
            #pragma unroll
            for (int ch = 0; ch < 4; ch++) {
                float4 a = qp4[((ch * 2) * Bz + b) * 128 + k0];
                float4 e = qp4[((ch * 2) * Bz + b) * 128 + k1];
                q0.x += a.x; q0.y += a.y; q0.z += a.z; q0.w += a.w;
                q1.x += e.x; q1.y += e.y; q1.z += e.z; q1.w += e.w;
            }
            float4 wcA = wc4[k0], wcB = wc4[k1];
            float4 wiA = wi4[k0], wiB = wi4[k1];
            #pragma unroll
            for (int j = 0; j < 8; j++) {
                int cc = bid * 8 + j;
                float v = vmean[b * Cz + cc];
                float acc = 0.0f;
                acc += tanhf(fmaf(v, wcA.x, q0.x)) * wiA.x;
                acc += tanhf(fmaf(v, wcA.y, q0.y)) * wiA.y;
                acc += tanhf(fmaf(v, wcA.z, q0.z)) * wiA.z;
                acc += tanhf(fmaf(v, wcA.w, q0.w)) * wiA.w;
                acc += tanhf(fmaf(v, wcB.x, q1.x)) * wiB.x;
                acc += tanhf(fmaf(v, wcB.y, q1.y)) * wiB.y;
                acc += tanhf(fmaf(v, wcB.z, q1.z)) * wiB.z;
                acc += tanhf(fmaf(v, wcB.w, q1.w)) * wiB.w;
                acc = waveReduce(acc);
                if (lane == 0) sL[j * 8 + b] = acc;
            }
            __syncthreads();
            if (tid < 64) {
                int j = tid >> 3, b2 = tid & 7;
                float m = -1e30f;
                #pragma unroll
                for (int q = 0; q < 8; q++) m = fmaxf(m, sL[j * 8 + q]);
                float s = 0.0f;
                #pragma unroll
                for (int q = 0; q < 8; q++) s += expf(sL[j * 8 + q] - m);
                beta[b2 * Cz + bid * 8 + j] = expf(sL[j * 8 + b2] - m) / s;
            }
            __syncthreads();
        }
        gridSync(++bt);

        // ========== C: partial einsum spart[ch][b][p][k] over 256-c chunk, 128-k tile ==========
        // block = (chunkC, ktileC, bC); 64p x 128k tile; 4x4 per-thread regs
        {
            float* As = smem + S_AS;        // [32][64]  (c x p, beta-scaled)
            float* Bs = smem + S_BS;        // [32][128] (c x k)
            int pq = tid >> 5;              // 16 groups x 4p
            int kq = tid & 31;              // 32 groups x 4k
            int k0 = ktileC * 128;
            float acc[4][4];
            #pragma unroll
            for (int i = 0; i < 4; i++)
                #pragma unroll
                for (int j = 0; j < 4; j++) acc[i][j] = 0.0f;

            for (int st = 0; st < 8; st++) {
                int c0 = chunkC * 256 + st * 32;
                {   // stage As: 512 f4, 1/thread
                    int cl = tid >> 4, p4 = tid & 15;
                    float btv = beta[bC * Cz + c0 + cl];
                    float4 ev = ((const float4*)enc)[(size_t)(bC * Cz + c0 + cl) * 16 + p4];
                    ((float4*)As)[cl * 16 + p4] = make_float4(ev.x * btv, ev.y * btv, ev.z * btv, ev.w * btv);
                }
                {   // stage Bs: 1024 f4, 2/thread
                    #pragma unroll
                    for (int j = 0; j < 2; j++) {
                        int idx = tid * 2 + j;
                        int cl = idx >> 5, kf = idx & 31;
                        ((float4*)Bs)[cl * 32 + kf] =
                            ((const float4*)W_s)[(size_t)(c0 + cl) * 128 + ktileC * 32 + kf];
                    }
                }
                __syncthreads();
                #pragma unroll 8
                for (int cc = 0; cc < 32; cc++) {
                    float4 av = *(const float4*)&As[cc * 64 + pq * 4];
                    float4 bv = *(const float4*)&Bs[cc * 128 + kq * 4];
                    acc[0][0] = fmaf(av.x, bv.x, acc[0][0]);
                    acc[0][1] = fmaf(av.x, bv.y, acc[0][1]);
                    acc[0][2] = fmaf(av.x, bv.z, acc[0][2]);
                    acc[0][3] = fmaf(av.x, bv.w, acc[0][3]);
                    acc[1][0] = fmaf(av.y, bv.x, acc[1][0]);
                    acc[1][1] = fmaf(av.y, bv.y, acc[1][1]);
                    acc[1][2] = fmaf(av.y, bv.z, acc[1][2]);
                    acc[1][3] = fmaf(av.y, bv.w, acc[1][3]);
                    acc[2][0] = fmaf(av.z, bv.x, acc[2][0]);
                    acc[2][1] = fmaf(av.z, bv.y, acc[2][1]);
                    acc[2][2] = fmaf(av.z, bv.z, acc[2][2]);
                    acc[2][3] = fmaf(av.z, bv.w, acc[2][3]);
                    acc[3][0] = fmaf(av.w, bv.x, acc[3][0]);
                    acc[3][1] = fmaf(av.w, bv.y, acc[3][1]);
                    acc[3][2] = fmaf(av.w, bv.z, acc[3][2]);
                    acc[3][3] = fmaf(av.w, bv.w, acc[3][3]);
                }
                __syncthreads();
            }
            float* dst = spart + (size_t)((chunkC * Bz + bC) * Pz) * Kz + k0 + kq * 4;
            #pragma unroll
            for (int i = 0; i < 4; i++) {
                int p = pq * 4 + i;
                *(float4*)&dst[(size_t)p * Kz] = make_float4(acc[i][0], acc[i][1], acc[i][2], acc[i][3]);
            }
        }
        gridSync(++bt);

        // ========== D: spatial scores (8-chunk sum, k-split, atomicAdd into scoreS) ==========
        {
            int p = bid >> 2, kqr = bid & 3;
            int b = bw;
            int kf = lane & 31;
            int sh = lane >> 5;
            int kg = kqr * 32 + kf;         // f4 index 0..127
            const float4* sp4 = (const float4*)spart;
            float sx = 0.f, sy = 0.f, sz = 0.f, sw = 0.f;
            #pragma unroll
            for (int i = 0; i < 4; i++) {
                int ch = sh * 4 + i;
                float4 tv = sp4[((size_t)(ch * Bz + b) * 64 + p) * 128 + kg];
                sx += tv.x; sy += tv.y; sz += tv.z; sw += tv.w;
            }
            sx += __shfl_xor(sx, 32); sy += __shfl_xor(sy, 32);
            sz += __shfl_xor(sz, 32); sw += __shfl_xor(sw, 32);
            float acc = 0.0f;
            if (sh == 0) {
                float4 q = ((const float4*)b_s)[kg];
                #pragma unroll
                for (int ch = 0; ch < 4; ch++) {
                    float4 tq = ((const float4*)qpart)[((ch * 2 + 1) * Bz + b) * 128 + kg];
                    q.x += tq.x; q.y += tq.y; q.z += tq.z; q.w += tq.w;
                }
                float4 wi = ((const float4*)W_i)[kg];
                acc = tanhf(sx + q.x) * wi.x + tanhf(sy + q.y) * wi.y +
                      tanhf(sz + q.z) * wi.z + tanhf(sw + q.w) * wi.w;
            }
            acc = waveReduce(acc);
            if (lane == 0) atomicAdd(&scoreS[b * 64 + p], acc);
        }
        gridSync(++bt);

        // ========== E: alpha softmax (in-reg) + awe -> xcat; emb/h segments ==========
        {
            int b = gw >> 8;
            int cg = gw & 255;
            float sc[8];
            #pragma unroll
            for (int bb = 0; bb < 8; bb++) sc[bb] = scoreS[bb * 64 + lane];
            float m = -1e30f;
            #pragma unroll
            for (int bb = 0; bb < 8; bb++) m = fmaxf(m, sc[bb]);
            float denom = 0.0f;
            #pragma unroll
            for (int bb = 0; bb < 8; bb++) denom += expf(sc[bb] - m);
            float aval = expf(sc[b] - m) / denom;   // alpha[b][p=lane]
            #pragma unroll
            for (int j = 0; j < 8; j++) {
                int cc = cg * 8 + j;
                float e = enc[(size_t)(b * Cz + cc) * 64 + lane];
                float v = waveReduce(e * aval);
                if (lane == 0) xcat[b * 3072 + Ez + cc] = beta[b * Cz + cc] * v * (1.0f / 64.0f);
            }
            int gid = bid * NT + tid;
            if (gid < 8192) {
                int b2 = gid >> 10, r = gid & 1023;
                if (r < Ez) xcat[b2 * 3072 + r] = emb[(size_t)caps[b2 * T1z + t] * Ez + r];
                else        xcat[b2 * 3072 + 2560 + (r - Ez)] = hbuf[b2 * Dz + (r - Ez)];
            }
        }
        gridSync(++bt);

        // ========== F: gates (LDS-cached weights) + LSTM cell, fused ==========
        // block = d-pair; wave = (e-quarter q, dd); xcat read direct from global (L2-hot)
        {
            float* gp = smem;               // partials: [bw][g][b] = 256 floats
            const float4* xc4 = (const float4*)xcat;
            const float4* wf4 = (const float4*)(smem + S_WF);
            int q = bw >> 1, dd = bw & 1;
            int b = lane >> 3, e8 = lane & 7;
            float accg[4] = {0.f, 0.f, 0.f, 0.f};
            #pragma unroll 4
            for (int i = 0; i < 24; i++) {
                int ef4 = q * 192 + i * 8 + e8;
                float4 xv = xc4[b * 768 + ef4];
                #pragma unroll
                for (int g = 0; g < 4; g++) {
                    float4 w = wf4[(g * 2 + dd) * 768 + ef4];
                    accg[g] = fmaf(xv.x, w.x, accg[g]);
                    accg[g] = fmaf(xv.y, w.y, accg[g]);
                    accg[g] = fmaf(xv.z, w.z, accg[g]);
                    accg[g] = fmaf(xv.w, w.w, accg[g]);
                }
            }
            #pragma unroll
            for (int mm = 1; mm < 8; mm <<= 1) {
                #pragma unroll
                for (int g = 0; g < 4; g++) accg[g] += __shfl_xor(accg[g], mm);
            }
            if (e8 == 0) {
                #pragma unroll
                for (int g = 0; g < 4; g++) gp[(bw * 4 + g) * 8 + b] = accg[g];
            }
            __syncthreads();
            if (tid < 16) {
                int b2 = tid & 7, ddd = tid >> 3;
                int d3 = bid * 2 + ddd;
                float gate[4];
                #pragma unroll
                for (int g = 0; g < 4; g++) {
                    float sum = 0.0f;
                    #pragma unroll
                    for (int qq = 0; qq < 4; qq++) sum += gp[((qq * 2 + ddd) * 4 + g) * 8 + b2];
                    gate[g] = sum + b_ih[g * 512 + d3] + b_hh[g * 512 + d3];
                }
                int ci = b2 * 512 + d3;
                float cn = sigf(gate[1]) * cbuf[ci] + sigf(gate[0]) * tanhf(gate[2]);
                cbuf[ci] = cn;
                float hn = sigf(gate[3]) * tanhf(cn);
                hbuf[ci] = hn;
                hhist[(t * 8 + b2) * 512 + d3] = hn;
            }
        }
        gridSync(++bt);
    }

    // ========== G: all predictions: out[96][20000] = h_hist @ W_fc^T ==========
    {
        int hr = bid & 1, vg = bid >> 1;
        if (vg < 125) {
            float4* hs4 = (float4*)smem;    // [48][128] f4 = 24576 floats (aliases WA/WF ok)
            const float4* hh4 = (const float4*)hhist + hr * 6144;
            #pragma unroll
            for (int i = 0; i < 12; i++) hs4[tid + i * 512] = hh4[tid + i * 512];
            __syncthreads();
            int r8 = lane >> 3, d8 = lane & 7;
            int v0 = vg * 160;
            #pragma unroll
            for (int bi = 0; bi < 2; bi++) {
                int vb = v0 + (bw * 2 + bi) * 10;
                float acc[10][6];
                #pragma unroll
                for (int vv = 0; vv < 10; vv++)
                    #pragma unroll
                    for (int rr = 0; rr < 6; rr++) acc[vv][rr] = 0.0f;
                for (int i = 0; i < 16; i++) {
                    float4 h6[6];
                    #pragma unroll
                    for (int rr = 0; rr < 6; rr++) h6[rr] = hs4[(r8 * 6 + rr) * 128 + i * 8 + d8];
                    #pragma unroll
                    for (int vv = 0; vv < 10; vv++) {
                        float4 w = ((const float4*)W_fc)[(size_t)(vb + vv) * 128 + i * 8 + d8];
                        #pragma unroll
                        for (int rr = 0; rr < 6; rr++) {
                            acc[vv][rr] = fmaf(w.x, h6[rr].x, acc[vv][rr]);
                            acc[vv][rr] = fmaf(w.y, h6[rr].y, acc[vv][rr]);
                            acc[vv][rr] = fmaf(w.z, h6[rr].z, acc[vv][rr]);
                            acc[vv][rr] = fmaf(w.w, h6[rr].w, acc[vv][rr]);
                        }
                    }
                }
                #pragma unroll
                for (int vv = 0; vv < 10; vv++) {
                    #pragma unroll
                    for (int rr = 0; rr < 6; rr++) {
                        float a = acc[vv][rr];
                        a += __shfl_xor(a, 1);
                        a += __shfl_xor(a, 2);
                        a += __shfl_xor(a, 4);
                        if (d8 == 0) {
                            int row = hr * 48 + r8 * 6 + rr;   // row = t*8 + b
                            int tt = row >> 3, b2 = row & 7;
                            out[((size_t)b2 * Tz + tt) * Vz + vb + vv] = a + b_fc[vb + vv];
                        }
                    }
                }
            }
        }
    }
}

extern "C" void kernel_launch(void* const* d_in, const int* in_sizes, int n_in,
                              void* d_out, int out_size, void* d_ws, size_t ws_size,
                              hipStream_t stream) {
    const float* enc      = (const float*)d_in[0];
    const int*   caps     = (const int*)d_in[1];
    const int*   caplen   = (const int*)d_in[2];
    const float* W_c      = (const float*)d_in[3];
    const float* W_hc     = (const float*)d_in[4];
    const float* W_i_hat  = (const float*)d_in[5];
    const float* b_c      = (const float*)d_in[6];
    const float* W_s      = (const float*)d_in[8];
    const float* W_hs     = (const float*)d_in[9];
    const float* W_i      = (const float*)d_in[10];
    const float* b_s      = (const float*)d_in[11];
    const float* emb      = (const float*)d_in[13];
    const float* W_ih     = (const float*)d_in[14];
    const float* W_hh     = (const float*)d_in[15];
    const float* b_ih     = (const float*)d_in[16];
    const float* b_hh     = (const float*)d_in[17];
    const float* W_init_h = (const float*)d_in[18];
    const float* b_init_h = (const float*)d_in[19];
    const float* W_init_c = (const float*)d_in[20];
    const float* b_init_c = (const float*)d_in[21];
    const float* W_fc     = (const float*)d_in[22];
    const float* b_fc     = (const float*)d_in[23];

    k_main<<<dim3(NB), dim3(NT), 0, stream>>>(
        enc, caps, caplen, W_c, b_c, W_i_hat, W_s, b_s, W_i, emb,
        W_ih, W_hh, b_ih, b_hh, W_init_h, b_init_h, W_init_c, b_init_c,
        W_hc, W_hs, W_fc, b_fc, (float*)d_out, (float*)d_ws);
}

// Round 4
// 1264.207 us; speedup vs baseline: 4.3056x; 1.1298x over previous
//
#include <hip/hip_runtime.h>

#define Bz 8
#define T1z 13
#define Tz 12
#define Vz 20000
#define Ez 512
#define Dz 512
#define Kz 512
#define Cz 2048
#define Pz 64
#define NB 256
#define NT 512

// ---- persistent-kernel grid barrier state (monotone generation counter) ----
__device__ unsigned g_slots[NB];
__device__ unsigned g_gen2;

__device__ __forceinline__ float waveReduce(float v) {
    #pragma unroll
    for (int off = 32; off > 0; off >>= 1) v += __shfl_xor(v, off);
    return v;
}

__device__ __forceinline__ float sigf(float x) { return 1.0f / (1.0f + expf(-x)); }

// Coherent (L1/L2-bypassing, NON-invalidating) load for multi-written intermediates.
// Emits global_load_dword sc0 sc1: reads the L3 coherence point directly, leaves all
// cached read-only data (enc, W_s, W_fc, ...) warm in L2 across barriers.
__device__ __forceinline__ float ldcv(const float* p) {
    return __hip_atomic_load(p, __ATOMIC_RELAXED, __HIP_MEMORY_SCOPE_AGENT);
}
__device__ __forceinline__ float4 ldcv4(const float4* p) {
    const float* q = (const float*)p;
    float4 r;
    r.x = ldcv(q); r.y = ldcv(q + 1); r.z = ldcv(q + 2); r.w = ldcv(q + 3);
    return r;
}

// Grid-wide barrier: RELAXED polls; ONE release store at arrival (wbl2 writeback of
// dirty lines -> L3, no invalidate). NO acquire/invalidate at exit: readers of
// cross-phase intermediates use ldcv() bypass loads instead, so L2 read-caches
// survive all barriers.
__device__ __forceinline__ void gridSync(unsigned target) {
    __syncthreads();
    if (threadIdx.x == 0) {
        __hip_atomic_store(&g_slots[blockIdx.x], target, __ATOMIC_RELEASE, __HIP_MEMORY_SCOPE_AGENT);
    }
    if (blockIdx.x == 0) {
        if (threadIdx.x < 64) {
            long guard = 0;
            for (;;) {
                bool ok = true;
                #pragma unroll
                for (int i = 0; i < 4; i++) {
                    unsigned v = __hip_atomic_load(&g_slots[threadIdx.x + i * 64],
                                                   __ATOMIC_RELAXED, __HIP_MEMORY_SCOPE_AGENT);
                    ok = ok && ((int)(v - target) >= 0);
                }
                if (__all(ok)) break;
                __builtin_amdgcn_s_sleep(2);
                if (++guard > (1L << 20)) break;
            }
            if (threadIdx.x == 0) {
                __hip_atomic_store(&g_gen2, target, __ATOMIC_RELEASE, __HIP_MEMORY_SCOPE_AGENT);
            }
        }
    } else if (threadIdx.x == 0) {
        long guard = 0;
        while ((int)(__hip_atomic_load(&g_gen2, __ATOMIC_RELAXED, __HIP_MEMORY_SCOPE_AGENT) - target) < 0) {
            __builtin_amdgcn_s_sleep(2);
            if (++guard > (1L << 20)) break;
        }
    }
    __syncthreads();
}

// LDS layout (floats): [0..6143] scratch (C: As 2048 + Bs 4096; B: sL; F: gp)
//                      [6144..8319] WA (A-phase weight slab, 128x17 padded)
//                      [8320..32895] WF (F-phase W_ih/W_hh rows, 8 x 768 float4)
// Total 32896 floats = 131,584 B (< 160 KiB, 1 block/CU). G aliases [0..24575].
#define S_AS 0
#define S_BS 2048
#define S_WA 6144
#define S_WF 8320

__global__ __launch_bounds__(NT, 2) void k_main(
    const float* __restrict__ enc, const int* __restrict__ caps, const int* __restrict__ caplen,
    const float* __restrict__ W_c, const float* __restrict__ b_c, const float* __restrict__ W_i_hat,
    const float* __restrict__ W_s, const float* __restrict__ b_s, const float* __restrict__ W_i,
    const float* __restrict__ emb,
    const float* __restrict__ W_ih, const float* __restrict__ W_hh,
    const float* __restrict__ b_ih, const float* __restrict__ b_hh,
    const float* __restrict__ W_init_h, const float* __restrict__ b_init_h,
    const float* __restrict__ W_init_c, const float* __restrict__ b_init_c,
    const float* __restrict__ W_hc, const float* __restrict__ W_hs,
    const float* __restrict__ W_fc, const float* __restrict__ b_fc,
    float* __restrict__ out, float* __restrict__ ws)
{
    __shared__ __align__(16) float smem[32896];

    float* vmean  = ws;                     // 16384  (single-write: cached reads OK)
    float* hbuf   = vmean + 16384;          // 4096   (multi-write: ldcv reads)
    float* cbuf   = hbuf + 4096;            // 4096   (multi-write: ldcv reads)
    float* qpart  = cbuf + 4096;            // 32768  (multi-write: ldcv reads)
    float* beta   = qpart + 32768;          // 16384  (multi-write: ldcv reads)
    float* scoreS = beta + 16384;           // 512    (multi-write: ldcv reads)
    float* xcat   = scoreS + 512;           // 24576  (multi-write: ldcv reads)
    float* hhist  = xcat + 24576;           // 49152  (each elem single-write: cached)
    float* spart  = hhist + 49152;          // 2097152 (multi-write: ldcv reads)

    const int tid  = threadIdx.x;
    const int bid  = blockIdx.x;
    const int lane = tid & 63;
    const int bw   = tid >> 6;              // wave in block: 0..7
    const int gw   = bid * 8 + bw;          // global wave: 0..2047

    unsigned bt = __hip_atomic_load(&g_gen2, __ATOMIC_RELAXED, __HIP_MEMORY_SCOPE_AGENT);

    // ---- A-phase decomposition for this block: (which, chunkA, ksub) ----
    const int whichA = bid >> 7;            // 0: W_hc, 1: W_hs
    const int chunkA = (bid >> 5) & 3;      // d-chunk of 128
    const int ksubA  = bid & 31;            // k-slab of 16

    // ---- C-phase decomposition: XCD-aware (xcd = bid&7 under round-robin dispatch) ----
    const int xcdC   = bid & 7;
    const int innC   = bid >> 3;
    const int chunkC = ((innC & 3) << 1) | (xcdC & 1);               // 0..7 (256 c each)
    const int ktileC = (((innC >> 2) & 1) << 1) | ((xcdC >> 1) & 1); // 0..3 (128 k each)
    const int bC     = ((innC >> 3) << 1) | ((xcdC >> 2) & 1);       // 0..7

    // ================= one-time LDS weight staging =================
    {
        // WF: this block's 8 LSTM rows (4 gates x d-pair), 8 x 768 float4
        float4* wf4 = (float4*)(smem + S_WF);
        const float4* wih4 = (const float4*)W_ih;   // row = 640 f4
        const float4* whh4 = (const float4*)W_hh;   // row = 128 f4
        #pragma unroll
        for (int i = 0; i < 12; i++) {
            int f4i = i * 512 + tid;                // 0..6143
            int r2  = f4i / 768;                    // 0..7 = g*2+dd
            int col = f4i - r2 * 768;
            int j   = (r2 >> 1) * 512 + bid * 2 + (r2 & 1);
            wf4[r2 * 768 + col] = (col < 640) ? wih4[(size_t)j * 640 + col]
                                              : whh4[(size_t)j * 128 + (col - 640)];
        }
        // WA: W_{hc|hs}[chunkA*128 .. +128][ksubA*16 .. +16], padded [128][17]
        const float* Wsel = whichA ? W_hs : W_hc;
        #pragma unroll
        for (int i = 0; i < 4; i++) {
            int e = i * 512 + tid;                  // 0..2047
            int d = e >> 4, kk = e & 15;
            smem[S_WA + d * 17 + kk] = Wsel[(size_t)(chunkA * 128 + d) * Kz + ksubA * 16 + kk];
        }
    }

    // ================= phase 0: tail fills + Vmean =================
    {
        int gid = bid * NT + tid;
        const int base = Bz * Tz * Vz;
        const int nCap = Bz * T1z;
        const int nAlp = Bz * Tz * Pz;
        if (gid < nCap + Bz + nAlp + Bz) {
            if (gid < nCap) out[base + gid] = (float)caps[gid];
            else if (gid < nCap + Bz) out[base + gid] = (float)(caplen[gid - nCap] - 1);
            else if (gid < nCap + Bz + nAlp) out[base + gid] = 0.0f;
            else out[base + gid] = (float)(gid - (nCap + Bz + nAlp));
        }
        #pragma unroll
        for (int j = 0; j < 8; j++) {
            int w = gw * 8 + j;
            float v = enc[(size_t)w * 64 + lane];
            v = waveReduce(v);
            if (lane == 0) vmean[w] = v * (1.0f / 64.0f);
        }
    }
    gridSync(++bt);

    // ================= phase 1: h0 / c0 =================
    {
        #pragma unroll
        for (int j = 0; j < 4; j++) {
            int o = gw * 4 + j;
            int which = o >> 12;
            int rem = o & 4095;
            int b = rem >> 9, d = rem & 511;
            const float* W = which ? W_init_c : W_init_h;
            float acc = 0.0f;
            #pragma unroll 4
            for (int i = 0; i < 32; i++) {
                int cc = i * 64 + lane;
                acc = fmaf(vmean[b * Cz + cc], W[(size_t)d * Cz + cc], acc);
            }
            acc = waveReduce(acc);
            if (lane == 0) {
                if (which) cbuf[rem] = acc + b_init_c[d];
                else       hbuf[rem] = acc + b_init_h[d];
            }
        }
    }
    gridSync(++bt);

    for (int t = 0; t < Tz; t++) {
        // ========== A: q projections from LDS-cached W slabs + zero scoreS ==========
        {
            int kk = (tid >> 2) & 15;
            int dq = tid & 3;
            const float* hb = hbuf + bw * Dz + chunkA * 128;
            float hreg[32];
            #pragma unroll
            for (int j = 0; j < 32; j++) hreg[j] = ldcv(&hb[j * 4 + dq]);
            float acc = 0.0f;
            #pragma unroll
            for (int j = 0; j < 32; j++)
                acc = fmaf(hreg[j], smem[S_WA + (j * 4 + dq) * 17 + kk], acc);
            acc += __shfl_xor(acc, 1);
            acc += __shfl_xor(acc, 2);
            if (dq == 0)
                qpart[(size_t)((chunkA * 2 + whichA) * Bz + bw) * Kz + ksubA * 16 + kk] = acc;
            if (bid == 255) scoreS[tid] = 0.0f;
        }
        gridSync(++bt);

        // ========== B: channel attention scores + batch softmax -> beta ==========
        {
            float* sL = smem;               // [8 c][8 b]
            int b = bw;
            const float4* qp4 = (const float4*)qpart;
            const float4* wc4 = (const float4*)W_c;
            const float4* bc4 = (const float4*)b_c;
            const float4* wi4 = (const float4*)W_i_hat;
            int k0 = lane, k1 = 64 + lane;
            float4 q0 = bc4[k0], q1 = bc4[k1];
            #pragma unroll
            for (int ch = 0; ch < 4; ch++) {
                float4 a = ldcv4(&qp4[((ch * 2) * Bz + b) * 128 + k0]);
                float4 e = ldcv4(&qp4[((ch * 2) * Bz + b) * 128 + k1]);
                q0.x += a.x; q0.y += a.y; q0.z += a.z; q0.w += a.w;
                q1.x += e.x; q1.y += e.y; q1.z += e.z; q1.w += e.w;
            }
            float4 wcA = wc4[k0], wcB = wc4[k1];
            float4 wiA = wi4[k0], wiB = wi4[k1];
            #pragma unroll
            for (int j = 0; j < 8; j++) {
                int cc = bid * 8 + j;
                float v = vmean[b * Cz + cc];
                float acc = 0.0f;
                acc += tanhf(fmaf(v, wcA.x, q0.x)) * wiA.x;
                acc += tanhf(fmaf(v, wcA.y, q0.y)) * wiA.y;
                acc += tanhf(fmaf(v, wcA.z, q0.z)) * wiA.z;
                acc += tanhf(fmaf(v, wcA.w, q0.w)) * wiA.w;
                acc += tanhf(fmaf(v, wcB.x, q1.x)) * wiB.x;
                acc += tanhf(fmaf(v, wcB.y, q1.y)) * wiB.y;
                acc += tanhf(fmaf(v, wcB.z, q1.z)) * wiB.z;
                acc += tanhf(fmaf(v, wcB.w, q1.w)) * wiB.w;
                acc = waveReduce(acc);
                if (lane == 0) sL[j * 8 + b] = acc;
            }
            __syncthreads();
            if (tid < 64) {
                int j = tid >> 3, b2 = tid & 7;
                float m = -1e30f;
                #pragma unroll
                for (int q = 0; q < 8; q++) m = fmaxf(m, sL[j * 8 + q]);
                float s = 0.0f;
                #pragma unroll
                for (int q = 0; q < 8; q++) s += expf(sL[j * 8 + q] - m);
                beta[b2 * Cz + bid * 8 + j] = expf(sL[j * 8 + b2] - m) / s;
            }
            __syncthreads();
        }
        gridSync(++bt);

        // ========== C: partial einsum spart[ch][b][p][k]; enc/W_s stay L2-warm ==========
        {
            float* As = smem + S_AS;        // [32][64]  (c x p, beta-scaled)
            float* Bs = smem + S_BS;        // [32][128] (c x k)
            int pq = tid >> 5;              // 16 groups x 4p
            int kq = tid & 31;              // 32 groups x 4k
            int k0 = ktileC * 128;
            float acc[4][4];
            #pragma unroll
            for (int i = 0; i < 4; i++)
                #pragma unroll
                for (int j = 0; j < 4; j++) acc[i][j] = 0.0f;

            for (int st = 0; st < 8; st++) {
                int c0 = chunkC * 256 + st * 32;
                {   // stage As: 512 f4, 1/thread (enc cached; beta bypass)
                    int cl = tid >> 4, p4 = tid & 15;
                    float btv = ldcv(&beta[bC * Cz + c0 + cl]);
                    float4 ev = ((const float4*)enc)[(size_t)(bC * Cz + c0 + cl) * 16 + p4];
                    ((float4*)As)[cl * 16 + p4] = make_float4(ev.x * btv, ev.y * btv, ev.z * btv, ev.w * btv);
                }
                {   // stage Bs: 1024 f4, 2/thread (W_s cached)
                    #pragma unroll
                    for (int j = 0; j < 2; j++) {
                        int idx = tid * 2 + j;
                        int cl = idx >> 5, kf = idx & 31;
                        ((float4*)Bs)[cl * 32 + kf] =
                            ((const float4*)W_s)[(size_t)(c0 + cl) * 128 + ktileC * 32 + kf];
                    }
                }
                __syncthreads();
                #pragma unroll 8
                for (int cc = 0; cc < 32; cc++) {
                    float4 av = *(const float4*)&As[cc * 64 + pq * 4];
                    float4 bv = *(const float4*)&Bs[cc * 128 + kq * 4];
                    acc[0][0] = fmaf(av.x, bv.x, acc[0][0]);
                    acc[0][1] = fmaf(av.x, bv.y, acc[0][1]);
                    acc[0][2] = fmaf(av.x, bv.z, acc[0][2]);
                    acc[0][3] = fmaf(av.x, bv.w, acc[0][3]);
                    acc[1][0] = fmaf(av.y, bv.x, acc[1][0]);
                    acc[1][1] = fmaf(av.y, bv.y, acc[1][1]);
                    acc[1][2] = fmaf(av.y, bv.z, acc[1][2]);
                    acc[1][3] = fmaf(av.y, bv.w, acc[1][3]);
                    acc[2][0] = fmaf(av.z, bv.x, acc[2][0]);
                    acc[2][1] = fmaf(av.z, bv.y, acc[2][1]);
                    acc[2][2] = fmaf(av.z, bv.z, acc[2][2]);
                    acc[2][3] = fmaf(av.z, bv.w, acc[2][3]);
                    acc[3][0] = fmaf(av.w, bv.x, acc[3][0]);
                    acc[3][1] = fmaf(av.w, bv.y, acc[3][1]);
                    acc[3][2] = fmaf(av.w, bv.z, acc[3][2]);
                    acc[3][3] = fmaf(av.w, bv.w, acc[3][3]);
                }
                __syncthreads();
            }
            float* dst = spart + (size_t)((chunkC * Bz + bC) * Pz) * Kz + k0 + kq * 4;
            #pragma unroll
            for (int i = 0; i < 4; i++) {
                int p = pq * 4 + i;
                *(float4*)&dst[(size_t)p * Kz] = make_float4(acc[i][0], acc[i][1], acc[i][2], acc[i][3]);
            }
        }
        gridSync(++bt);

        // ========== D: spatial scores (8-chunk sum, k-split, atomicAdd into scoreS) ==========
        {
            int p = bid >> 2, kqr = bid & 3;
            int b = bw;
            int kf = lane & 31;
            int sh = lane >> 5;
            int kg = kqr * 32 + kf;         // f4 index 0..127
            const float4* sp4 = (const float4*)spart;
            float sx = 0.f, sy = 0.f, sz = 0.f, sw = 0.f;
            #pragma unroll
            for (int i = 0; i < 4; i++) {
                int ch = sh * 4 + i;
                float4 tv = ldcv4(&sp4[((size_t)(ch * Bz + b) * 64 + p) * 128 + kg]);
                sx += tv.x; sy += tv.y; sz += tv.z; sw += tv.w;
            }
            sx += __shfl_xor(sx, 32); sy += __shfl_xor(sy, 32);
            sz += __shfl_xor(sz, 32); sw += __shfl_xor(sw, 32);
            float acc = 0.0f;
            if (sh == 0) {
                float4 q = ((const float4*)b_s)[kg];
                #pragma unroll
                for (int ch = 0; ch < 4; ch++) {
                    float4 tq = ldcv4(&((const float4*)qpart)[((ch * 2 + 1) * Bz + b) * 128 + kg]);
                    q.x += tq.x; q.y += tq.y; q.z += tq.z; q.w += tq.w;
                }
                float4 wi = ((const float4*)W_i)[kg];
                acc = tanhf(sx + q.x) * wi.x + tanhf(sy + q.y) * wi.y +
                      tanhf(sz + q.z) * wi.z + tanhf(sw + q.w) * wi.w;
            }
            acc = waveReduce(acc);
            if (lane == 0) atomicAdd(&scoreS[b * 64 + p], acc);
        }
        gridSync(++bt);

        // ========== E: alpha softmax (in-reg) + awe -> xcat; emb/h segments ==========
        {
            int b = gw >> 8;
            int cg = gw & 255;
            float sc[8];
            #pragma unroll
            for (int bb = 0; bb < 8; bb++) sc[bb] = ldcv(&scoreS[bb * 64 + lane]);
            float m = -1e30f;
            #pragma unroll
            for (int bb = 0; bb < 8; bb++) m = fmaxf(m, sc[bb]);
            float denom = 0.0f;
            #pragma unroll
            for (int bb = 0; bb < 8; bb++) denom += expf(sc[bb] - m);
            float aval = expf(sc[b] - m) / denom;   // alpha[b][p=lane]
            // beta for this wave's 8 channels, batched bypass load then shfl-broadcast
            float bv = (lane < 8) ? ldcv(&beta[b * Cz + cg * 8 + lane]) : 0.0f;
            #pragma unroll
            for (int j = 0; j < 8; j++) {
                int cc = cg * 8 + j;
                float e = enc[(size_t)(b * Cz + cc) * 64 + lane];
                float v = waveReduce(e * aval);
                float bj = __shfl(bv, j);
                if (lane == 0) xcat[b * 3072 + Ez + cc] = bj * v * (1.0f / 64.0f);
            }
            int gid = bid * NT + tid;
            if (gid < 8192) {
                int b2 = gid >> 10, r = gid & 1023;
                if (r < Ez) xcat[b2 * 3072 + r] = emb[(size_t)caps[b2 * T1z + t] * Ez + r];
                else        xcat[b2 * 3072 + 2560 + (r - Ez)] = ldcv(&hbuf[b2 * Dz + (r - Ez)]);
            }
        }
        gridSync(++bt);

        // ========== F: gates (LDS-cached weights) + LSTM cell, fused ==========
        // wave bw = e-eighth (96 f4); each wave computes ALL 8 gate-rows -> xcat read 1x
        {
            float* gp = smem;               // partials: [8 waves][8 rows][8 b] = 512 floats
            const float4* xc4 = (const float4*)xcat;
            const float4* wf4 = (const float4*)(smem + S_WF);
            int b = lane >> 3, e8 = lane & 7;
            float accg[8] = {0.f, 0.f, 0.f, 0.f, 0.f, 0.f, 0.f, 0.f};
            #pragma unroll 3
            for (int i = 0; i < 12; i++) {
                int ef4 = bw * 96 + i * 8 + e8;
                float4 xv = ldcv4(&xc4[b * 768 + ef4]);
                #pragma unroll
                for (int r2 = 0; r2 < 8; r2++) {
                    float4 w = wf4[r2 * 768 + ef4];
                    accg[r2] = fmaf(xv.x, w.x, accg[r2]);
                    accg[r2] = fmaf(xv.y, w.y, accg[r2]);
                    accg[r2] = fmaf(xv.z, w.z, accg[r2]);
                    accg[r2] = fmaf(xv.w, w.w, accg[r2]);
                }
            }
            #pragma unroll
            for (int mm = 1; mm < 8; mm <<= 1) {
                #pragma unroll
                for (int r2 = 0; r2 < 8; r2++) accg[r2] += __shfl_xor(accg[r2], mm);
            }
            if (e8 == 0) {
                #pragma unroll
                for (int r2 = 0; r2 < 8; r2++) gp[(bw * 8 + r2) * 8 + b] = accg[r2];
            }
            __syncthreads();
            if (tid < 16) {
                int b2 = tid & 7, ddd = tid >> 3;
                int d3 = bid * 2 + ddd;
                float gate[4];
                #pragma unroll
                for (int g = 0; g < 4; g++) {
                    float sum = 0.0f;
                    #pragma unroll
                    for (int qq = 0; qq < 8; qq++) sum += gp[(qq * 8 + g * 2 + ddd) * 8 + b2];
                    gate[g] = sum + b_ih[g * 512 + d3] + b_hh[g * 512 + d3];
                }
                int ci = b2 * 512 + d3;
                float cn = sigf(gate[1]) * ldcv(&cbuf[ci]) + sigf(gate[0]) * tanhf(gate[2]);
                cbuf[ci] = cn;
                float hn = sigf(gate[3]) * tanhf(cn);
                hbuf[ci] = hn;
                hhist[(t * 8 + b2) * 512 + d3] = hn;
            }
        }
        gridSync(++bt);
    }

    // ========== G: all predictions: out[96][20000] = h_hist @ W_fc^T ==========
    {
        int hr = bid & 1, vg = bid >> 1;
        if (vg < 125) {
            float4* hs4 = (float4*)smem;    // [48][128] f4 (aliases WA/WF — t-loop done)
            const float4* hh4 = (const float4*)hhist + hr * 6144;
            #pragma unroll
            for (int i = 0; i < 12; i++) hs4[tid + i * 512] = hh4[tid + i * 512];
            __syncthreads();
            int r8 = lane >> 3, d8 = lane & 7;
            int v0 = vg * 160;
            #pragma unroll
            for (int bi = 0; bi < 2; bi++) {
                int vb = v0 + (bw * 2 + bi) * 10;
                float acc[10][6];
                #pragma unroll
                for (int vv = 0; vv < 10; vv++)
                    #pragma unroll
                    for (int rr = 0; rr < 6; rr++) acc[vv][rr] = 0.0f;
                for (int i = 0; i < 16; i++) {
                    float4 h6[6];
                    #pragma unroll
                    for (int rr = 0; rr < 6; rr++) h6[rr] = hs4[(r8 * 6 + rr) * 128 + i * 8 + d8];
                    #pragma unroll
                    for (int vv = 0; vv < 10; vv++) {
                        float4 w = ((const float4*)W_fc)[(size_t)(vb + vv) * 128 + i * 8 + d8];
                        #pragma unroll
                        for (int rr = 0; rr < 6; rr++) {
                            acc[vv][rr] = fmaf(w.x, h6[rr].x, acc[vv][rr]);
                            acc[vv][rr] = fmaf(w.y, h6[rr].y, acc[vv][rr]);
                            acc[vv][rr] = fmaf(w.z, h6[rr].z, acc[vv][rr]);
                            acc[vv][rr] = fmaf(w.w, h6[rr].w, acc[vv][rr]);
                        }
                    }
                }
                #pragma unroll
                for (int vv = 0; vv < 10; vv++) {
                    #pragma unroll
                    for (int rr = 0; rr < 6; rr++) {
                        float a = acc[vv][rr];
                        a += __shfl_xor(a, 1);
                        a += __shfl_xor(a, 2);
                        a += __shfl_xor(a, 4);
                        if (d8 == 0) {
                            int row = hr * 48 + r8 * 6 + rr;   // row = t*8 + b
                            int tt = row >> 3, b2 = row & 7;
                            out[((size_t)b2 * Tz + tt) * Vz + vb + vv] = a + b_fc[vb + vv];
                        }
                    }
                }
            }
        }
    }
}

extern "C" void kernel_launch(void* const* d_in, const int* in_sizes, int n_in,
                              void* d_out, int out_size, void* d_ws, size_t ws_size,
                              hipStream_t stream) {
    const float* enc      = (const float*)d_in[0];
    const int*   caps     = (const int*)d_in[1];
    const int*   caplen   = (const int*)d_in[2];
    const float* W_c      = (const float*)d_in[3];
    const float* W_hc     = (const float*)d_in[4];
    const float* W_i_hat  = (const float*)d_in[5];
    const float* b_c      = (const float*)d_in[6];
    const float* W_s      = (const float*)d_in[8];
    const float* W_hs     = (const float*)d_in[9];
    const float* W_i      = (const float*)d_in[10];
    const float* b_s      = (const float*)d_in[11];
    const float* emb      = (const float*)d_in[13];
    const float* W_ih     = (const float*)d_in[14];
    const float* W_hh     = (const float*)d_in[15];
    const float* b_ih     = (const float*)d_in[16];
    const float* b_hh     = (const float*)d_in[17];
    const float* W_init_h = (const float*)d_in[18];
    const float* b_init_h = (const float*)d_in[19];
    const float* W_init_c = (const float*)d_in[20];
    const float* b_init_c = (const float*)d_in[21];
    const float* W_fc     = (const float*)d_in[22];
    const float* b_fc     = (const float*)d_in[23];

    k_main<<<dim3(NB), dim3(NT), 0, stream>>>(
        enc, caps, caplen, W_c, b_c, W_i_hat, W_s, b_s, W_i, emb,
        W_ih, W_hh, b_ih, b_hh, W_init_h, b_init_h, W_init_c, b_init_c,
        W_hc, W_hs, W_fc, b_fc, (float*)d_out, (float*)d_ws);
}

// Round 6
// 1218.336 us; speedup vs baseline: 4.4677x; 1.0377x over previous
//
#include <hip/hip_runtime.h>

#define Bz 8
#define T1z 13
#define Tz 12
#define Vz 20000
#define Ez 512
#define Dz 512
#define Kz 512
#define Cz 2048
#define Pz 64
#define NB 256
#define NT 512

typedef float floatx4 __attribute__((ext_vector_type(4)));

// ---- persistent-kernel grid barrier state (monotone generation counter) ----
__device__ unsigned g_slots[NB];
__device__ unsigned g_gen2;

__device__ __forceinline__ float waveReduce(float v) {
    #pragma unroll
    for (int off = 32; off > 0; off >>= 1) v += __shfl_xor(v, off);
    return v;
}

__device__ __forceinline__ float sigf(float x) { return 1.0f / (1.0f + expf(-x)); }

// Coherent (L1/L2-bypassing, NON-invalidating) scalar load for small cases.
__device__ __forceinline__ float ldcv(const float* p) {
    return __hip_atomic_load(p, __ATOMIC_RELAXED, __HIP_MEMORY_SCOPE_AGENT);
}

// Vector (dwordx4) coherent bypass loads: 1 instruction / 16B instead of 4 scalars
// (bypass loads never fill L2, so scalar xyzw re-fetched the same L3 line 4x).
// Batched variants issue N loads before ONE waitcnt -> single L3 latency.
__device__ __forceinline__ float4 ldcv4a(const float4* p) {
    float4 r;
    asm volatile("global_load_dwordx4 %0, %1, off sc0 sc1\n\ts_waitcnt vmcnt(0)"
                 : "=&v"(r) : "v"(p) : "memory");
    return r;
}
__device__ __forceinline__ void ldcv4x2(float4& a, float4& b,
                                        const float4* pa, const float4* pb) {
    asm volatile("global_load_dwordx4 %0, %2, off sc0 sc1\n\t"
                 "global_load_dwordx4 %1, %3, off sc0 sc1\n\t"
                 "s_waitcnt vmcnt(0)"
                 : "=&v"(a), "=&v"(b) : "v"(pa), "v"(pb) : "memory");
}
__device__ __forceinline__ void ldcv4x4(float4& a, float4& b, float4& c, float4& d,
                                        const float4* pa, const float4* pb,
                                        const float4* pc, const float4* pd) {
    asm volatile("global_load_dwordx4 %0, %4, off sc0 sc1\n\t"
                 "global_load_dwordx4 %1, %5, off sc0 sc1\n\t"
                 "global_load_dwordx4 %2, %6, off sc0 sc1\n\t"
                 "global_load_dwordx4 %3, %7, off sc0 sc1\n\t"
                 "s_waitcnt vmcnt(0)"
                 : "=&v"(a), "=&v"(b), "=&v"(c), "=&v"(d)
                 : "v"(pa), "v"(pb), "v"(pc), "v"(pd) : "memory");
}
// Coherent write-through store: goes straight to L3, leaves no dirty L2 lines.
// NOTE: value must be an ext_vector_type (first-class vector), not the float4
// struct — clang can't pass struct inputs in a 'v' constraint ("indirect
// register inputs"); struct OUTPUTS are fine (see ldcv4* above).
__device__ __forceinline__ void stcv4(float4* p, float4 v) {
    floatx4 w;
    w.x = v.x; w.y = v.y; w.z = v.z; w.w = v.w;
    asm volatile("global_store_dwordx4 %0, %1, off sc0 sc1" :: "v"(p), "v"(w) : "memory");
}

// Grid-wide barrier: RELAXED polls; ONE release store at arrival. No invalidate:
// cross-phase intermediates are read via bypass loads, L2 read-caches survive.
__device__ __forceinline__ void gridSync(unsigned target) {
    __syncthreads();
    if (threadIdx.x == 0) {
        __hip_atomic_store(&g_slots[blockIdx.x], target, __ATOMIC_RELEASE, __HIP_MEMORY_SCOPE_AGENT);
    }
    if (blockIdx.x == 0) {
        if (threadIdx.x < 64) {
            long guard = 0;
            for (;;) {
                bool ok = true;
                #pragma unroll
                for (int i = 0; i < 4; i++) {
                    unsigned v = __hip_atomic_load(&g_slots[threadIdx.x + i * 64],
                                                   __ATOMIC_RELAXED, __HIP_MEMORY_SCOPE_AGENT);
                    ok = ok && ((int)(v - target) >= 0);
                }
                if (__all(ok)) break;
                __builtin_amdgcn_s_sleep(2);
                if (++guard > (1L << 20)) break;
            }
            if (threadIdx.x == 0) {
                __hip_atomic_store(&g_gen2, target, __ATOMIC_RELEASE, __HIP_MEMORY_SCOPE_AGENT);
            }
        }
    } else if (threadIdx.x == 0) {
        long guard = 0;
        while ((int)(__hip_atomic_load(&g_gen2, __ATOMIC_RELAXED, __HIP_MEMORY_SCOPE_AGENT) - target) < 0) {
            __builtin_amdgcn_s_sleep(2);
            if (++guard > (1L << 20)) break;
        }
    }
    __syncthreads();
}

// LDS layout (floats): [0..8191] scratch (A: hS 4096 + partials 4096; C: As 2048 + Bs 4096;
//                       B: sL 64; E: scoreS stage 512; F: gp 512)
//                      [8192..32767] WF (F-phase W_ih/W_hh rows, 8 x 768 float4)
// Total 32768 floats = 131,072 B (1 block/CU). G aliases [0..24575] (t-loop done).
#define S_WF 8192

__global__ __launch_bounds__(NT, 2) void k_main(
    const float* __restrict__ enc, const int* __restrict__ caps, const int* __restrict__ caplen,
    const float* __restrict__ W_c, const float* __restrict__ b_c, const float* __restrict__ W_i_hat,
    const float* __restrict__ W_s, const float* __restrict__ b_s, const float* __restrict__ W_i,
    const float* __restrict__ emb,
    const float* __restrict__ W_ih, const float* __restrict__ W_hh,
    const float* __restrict__ b_ih, const float* __restrict__ b_hh,
    const float* __restrict__ W_init_h, const float* __restrict__ b_init_h,
    const float* __restrict__ W_init_c, const float* __restrict__ b_init_c,
    const float* __restrict__ W_hc, const float* __restrict__ W_hs,
    const float* __restrict__ W_fc, const float* __restrict__ b_fc,
    float* __restrict__ out, float* __restrict__ ws)
{
    __shared__ __align__(16) float smem[32768];

    float* vmean  = ws;                     // 16384  (single-write: cached reads OK)
    float* hbuf   = vmean + 16384;          // 4096   (multi-write: bypass reads)
    float* cbuf   = hbuf + 4096;            // 4096
    float* qpart  = cbuf + 4096;            // 2which*8b*512k = 8192 (FINAL sums now)
    float* beta   = qpart + 8192;           // 16384
    float* scoreS = beta + 16384;           // 512  [b][p]
    float* xcat   = scoreS + 512;           // 8*3072 = 24576
    float* hhist  = xcat + 24576;           // 96*512 = 49152
    float* spart  = hhist + 49152;          // 8ch*8b*64p*512k = 2097152 (8.4 MB)

    const int tid  = threadIdx.x;
    const int bid  = blockIdx.x;
    const int lane = tid & 63;
    const int bw   = tid >> 6;              // wave in block: 0..7
    const int gw   = bid * 8 + bw;          // global wave: 0..2047

    unsigned bt = __hip_atomic_load(&g_gen2, __ATOMIC_RELAXED, __HIP_MEMORY_SCOPE_AGENT);

    // ---- C-phase decomposition: XCD-aware (xcd = bid&7 under round-robin dispatch) ----
    const int xcdC   = bid & 7;
    const int innC   = bid >> 3;
    const int chunkC = ((innC & 3) << 1) | (xcdC & 1);               // 0..7 (256 c each)
    const int ktileC = (((innC >> 2) & 1) << 1) | ((xcdC >> 1) & 1); // 0..3 (128 k each)
    const int bC     = ((innC >> 3) << 1) | ((xcdC >> 2) & 1);       // 0..7

    // ================= one-time LDS weight staging (WF) =================
    {
        float4* wf4 = (float4*)(smem + S_WF);
        const float4* wih4 = (const float4*)W_ih;   // row = 640 f4
        const float4* whh4 = (const float4*)W_hh;   // row = 128 f4
        #pragma unroll
        for (int i = 0; i < 12; i++) {
            int f4i = i * 512 + tid;                // 0..6143
            int r2  = f4i / 768;                    // 0..7 = g*2+dd
            int col = f4i - r2 * 768;
            int j   = (r2 >> 1) * 512 + bid * 2 + (r2 & 1);
            wf4[r2 * 768 + col] = (col < 640) ? wih4[(size_t)j * 640 + col]
                                              : whh4[(size_t)j * 128 + (col - 640)];
        }
    }

    // ================= phase 0: tail fills + Vmean =================
    {
        int gid = bid * NT + tid;
        const int base = Bz * Tz * Vz;
        const int nCap = Bz * T1z;
        const int nAlp = Bz * Tz * Pz;
        if (gid < nCap + Bz + nAlp + Bz) {
            if (gid < nCap) out[base + gid] = (float)caps[gid];
            else if (gid < nCap + Bz) out[base + gid] = (float)(caplen[gid - nCap] - 1);
            else if (gid < nCap + Bz + nAlp) out[base + gid] = 0.0f;
            else out[base + gid] = (float)(gid - (nCap + Bz + nAlp));
        }
        #pragma unroll
        for (int j = 0; j < 8; j++) {
            int w = gw * 8 + j;
            float v = enc[(size_t)w * 64 + lane];
            v = waveReduce(v);
            if (lane == 0) vmean[w] = v * (1.0f / 64.0f);
        }
    }
    gridSync(++bt);

    // ================= phase 1: h0 / c0 =================
    {
        #pragma unroll
        for (int j = 0; j < 4; j++) {
            int o = gw * 4 + j;
            int which = o >> 12;
            int rem = o & 4095;
            int b = rem >> 9, d = rem & 511;
            const float* W = which ? W_init_c : W_init_h;
            float acc = 0.0f;
            #pragma unroll 4
            for (int i = 0; i < 32; i++) {
                int cc = i * 64 + lane;
                acc = fmaf(vmean[b * Cz + cc], W[(size_t)d * Cz + cc], acc);
            }
            acc = waveReduce(acc);
            if (lane == 0) {
                if (which) cbuf[rem] = acc + b_init_c[d];
                else       hbuf[rem] = acc + b_init_h[d];
            }
        }
    }
    gridSync(++bt);

    for (int t = 0; t < Tz; t++) {
        // ========== A: FINAL q projections, 32 blocks (which, kslab of 32k) ==========
        // h (all 8 b) staged to LDS; W column-slab (64KB) cached/L2-warm; d-group
        // partials tree-reduced in LDS -> qpart holds final sums (B reads 1 f4, D 1 f4).
        {
            if (bid < 32) {
                const int whichA = bid & 1, kslabA = bid >> 1;
                const float* Wsel = whichA ? W_hs : W_hc;
                {   // stage hbuf[8][512] -> smem[0..4095]
                    const float4* hb4 = (const float4*)hbuf;
                    float4 a, b;
                    ldcv4x2(a, b, hb4 + tid * 2, hb4 + tid * 2 + 1);
                    ((float4*)smem)[tid * 2]     = a;
                    ((float4*)smem)[tid * 2 + 1] = b;
                }
                __syncthreads();
                int kk = tid & 31, dg = tid >> 5;   // dg 0..15
                int k = kslabA * 32 + kk;
                float acc[8] = {0.f, 0.f, 0.f, 0.f, 0.f, 0.f, 0.f, 0.f};
                #pragma unroll 8
                for (int j = 0; j < 32; j++) {
                    int d = dg * 32 + j;
                    float wv = Wsel[(size_t)d * Kz + k];
                    #pragma unroll
                    for (int b = 0; b < 8; b++) acc[b] = fmaf(smem[b * 512 + d], wv, acc[b]);
                }
                #pragma unroll
                for (int b = 0; b < 8; b++) smem[4096 + dg * 256 + b * 32 + kk] = acc[b];
                __syncthreads();
                if (tid < 256) {
                    int b = tid >> 5, kk2 = tid & 31;
                    float s = 0.0f;
                    #pragma unroll
                    for (int dg2 = 0; dg2 < 16; dg2++) s += smem[4096 + dg2 * 256 + b * 32 + kk2];
                    qpart[(size_t)(whichA * 8 + b) * Kz + kslabA * 32 + kk2] = s;
                }
            }
            if (bid == 255) scoreS[tid] = 0.0f;
        }
        gridSync(++bt);

        // ========== B: channel attention scores + batch softmax -> beta ==========
        {
            float* sL = smem;               // [8 c][8 b]
            int b = bw;
            const float4* wc4 = (const float4*)W_c;
            const float4* bc4 = (const float4*)b_c;
            const float4* wi4 = (const float4*)W_i_hat;
            int k0 = lane, k1 = 64 + lane;
            const float4* qb = (const float4*)qpart + b * 128 + k0;
            float4 qa, qe;
            ldcv4x2(qa, qe, qb, qb + 64);
            float4 q0 = bc4[k0], q1 = bc4[k1];
            q0.x += qa.x; q0.y += qa.y; q0.z += qa.z; q0.w += qa.w;
            q1.x += qe.x; q1.y += qe.y; q1.z += qe.z; q1.w += qe.w;
            float4 wcA = wc4[k0], wcB = wc4[k1];
            float4 wiA = wi4[k0], wiB = wi4[k1];
            #pragma unroll
            for (int j = 0; j < 8; j++) {
                int cc = bid * 8 + j;
                float v = vmean[b * Cz + cc];
                float acc = 0.0f;
                acc += tanhf(fmaf(v, wcA.x, q0.x)) * wiA.x;
                acc += tanhf(fmaf(v, wcA.y, q0.y)) * wiA.y;
                acc += tanhf(fmaf(v, wcA.z, q0.z)) * wiA.z;
                acc += tanhf(fmaf(v, wcA.w, q0.w)) * wiA.w;
                acc += tanhf(fmaf(v, wcB.x, q1.x)) * wiB.x;
                acc += tanhf(fmaf(v, wcB.y, q1.y)) * wiB.y;
                acc += tanhf(fmaf(v, wcB.z, q1.z)) * wiB.z;
                acc += tanhf(fmaf(v, wcB.w, q1.w)) * wiB.w;
                acc = waveReduce(acc);
                if (lane == 0) sL[j * 8 + b] = acc;
            }
            __syncthreads();
            if (tid < 64) {
                int j = tid >> 3, b2 = tid & 7;
                float m = -1e30f;
                #pragma unroll
                for (int q = 0; q < 8; q++) m = fmaxf(m, sL[j * 8 + q]);
                float s = 0.0f;
                #pragma unroll
                for (int q = 0; q < 8; q++) s += expf(sL[j * 8 + q] - m);
                beta[b2 * Cz + bid * 8 + j] = expf(sL[j * 8 + b2] - m) / s;
            }
            __syncthreads();
        }
        gridSync(++bt);

        // ========== C: partial einsum spart[ch][b][p][k]; enc/W_s stay L2-warm ==========
        {
            float* As = smem;               // [32][64]  (c x p, beta-scaled)
            float* Bs = smem + 2048;        // [32][128] (c x k)
            int pq = tid >> 5;              // 16 groups x 4p
            int kq = tid & 31;              // 32 groups x 4k
            int k0 = ktileC * 128;
            float acc[4][4];
            #pragma unroll
            for (int i = 0; i < 4; i++)
                #pragma unroll
                for (int j = 0; j < 4; j++) acc[i][j] = 0.0f;

            for (int st = 0; st < 8; st++) {
                int c0 = chunkC * 256 + st * 32;
                {   // stage As: 512 f4, 1/thread (enc cached; beta bypass)
                    int cl = tid >> 4, p4 = tid & 15;
                    float btv = ldcv(&beta[bC * Cz + c0 + cl]);
                    float4 ev = ((const float4*)enc)[(size_t)(bC * Cz + c0 + cl) * 16 + p4];
                    ((float4*)As)[cl * 16 + p4] = make_float4(ev.x * btv, ev.y * btv, ev.z * btv, ev.w * btv);
                }
                {   // stage Bs: 1024 f4, 2/thread (W_s cached)
                    #pragma unroll
                    for (int j = 0; j < 2; j++) {
                        int idx = tid * 2 + j;
                        int cl = idx >> 5, kf = idx & 31;
                        ((float4*)Bs)[cl * 32 + kf] =
                            ((const float4*)W_s)[(size_t)(c0 + cl) * 128 + ktileC * 32 + kf];
                    }
                }
                __syncthreads();
                #pragma unroll 8
                for (int cc = 0; cc < 32; cc++) {
                    float4 av = *(const float4*)&As[cc * 64 + pq * 4];
                    float4 bv = *(const float4*)&Bs[cc * 128 + kq * 4];
                    acc[0][0] = fmaf(av.x, bv.x, acc[0][0]);
                    acc[0][1] = fmaf(av.x, bv.y, acc[0][1]);
                    acc[0][2] = fmaf(av.x, bv.z, acc[0][2]);
                    acc[0][3] = fmaf(av.x, bv.w, acc[0][3]);
                    acc[1][0] = fmaf(av.y, bv.x, acc[1][0]);
                    acc[1][1] = fmaf(av.y, bv.y, acc[1][1]);
                    acc[1][2] = fmaf(av.y, bv.z, acc[1][2]);
                    acc[1][3] = fmaf(av.y, bv.w, acc[1][3]);
                    acc[2][0] = fmaf(av.z, bv.x, acc[2][0]);
                    acc[2][1] = fmaf(av.z, bv.y, acc[2][1]);
                    acc[2][2] = fmaf(av.z, bv.z, acc[2][2]);
                    acc[2][3] = fmaf(av.z, bv.w, acc[2][3]);
                    acc[3][0] = fmaf(av.w, bv.x, acc[3][0]);
                    acc[3][1] = fmaf(av.w, bv.y, acc[3][1]);
                    acc[3][2] = fmaf(av.w, bv.z, acc[3][2]);
                    acc[3][3] = fmaf(av.w, bv.w, acc[3][3]);
                }
                __syncthreads();
            }
            float* dst = spart + (size_t)((chunkC * Bz + bC) * Pz) * Kz + k0 + kq * 4;
            #pragma unroll
            for (int i = 0; i < 4; i++) {
                int p = pq * 4 + i;
                stcv4((float4*)&dst[(size_t)p * Kz],
                      make_float4(acc[i][0], acc[i][1], acc[i][2], acc[i][3]));
            }
        }
        gridSync(++bt);

        // ========== D: spatial scores (8-chunk sum, k-split, atomicAdd into scoreS) ==========
        {
            int p = bid >> 2, kqr = bid & 3;
            int b = bw;
            int kf = lane & 31;
            int sh = lane >> 5;
            int kg = kqr * 32 + kf;         // f4 index 0..127
            const float4* sp4 = (const float4*)spart;
            size_t base = ((size_t)((sh * 4) * Bz + b) * 64 + p) * 128 + kg;
            const size_t chs = (size_t)Bz * 64 * 128;   // ch stride in f4
            float4 t0, t1, t2, t3;
            ldcv4x4(t0, t1, t2, t3, sp4 + base, sp4 + base + chs,
                    sp4 + base + 2 * chs, sp4 + base + 3 * chs);
            float sx = t0.x + t1.x + t2.x + t3.x;
            float sy = t0.y + t1.y + t2.y + t3.y;
            float sz = t0.z + t1.z + t2.z + t3.z;
            float sw = t0.w + t1.w + t2.w + t3.w;
            sx += __shfl_xor(sx, 32); sy += __shfl_xor(sy, 32);
            sz += __shfl_xor(sz, 32); sw += __shfl_xor(sw, 32);
            float acc = 0.0f;
            if (sh == 0) {
                float4 q = ((const float4*)b_s)[kg];
                float4 tq = ldcv4a(&((const float4*)qpart)[(8 + b) * 128 + kg]);
                q.x += tq.x; q.y += tq.y; q.z += tq.z; q.w += tq.w;
                float4 wi = ((const float4*)W_i)[kg];
                acc = tanhf(sx + q.x) * wi.x + tanhf(sy + q.y) * wi.y +
                      tanhf(sz + q.z) * wi.z + tanhf(sw + q.w) * wi.w;
            }
            acc = waveReduce(acc);
            if (lane == 0) atomicAdd(&scoreS[b * 64 + p], acc);
        }
        gridSync(++bt);

        // ========== E: alpha softmax (scoreS staged to LDS) + awe -> xcat ==========
        {
            if (tid < 128) {
                float4 s4 = ldcv4a(((const float4*)scoreS) + tid);
                ((float4*)smem)[tid] = s4;
            }
            __syncthreads();
            int b = gw >> 8;
            int cg = gw & 255;
            float sc[8];
            #pragma unroll
            for (int bb = 0; bb < 8; bb++) sc[bb] = smem[bb * 64 + lane];
            float m = -1e30f;
            #pragma unroll
            for (int bb = 0; bb < 8; bb++) m = fmaxf(m, sc[bb]);
            float denom = 0.0f;
            #pragma unroll
            for (int bb = 0; bb < 8; bb++) denom += expf(sc[bb] - m);
            float aval = expf(sc[b] - m) / denom;   // alpha[b][p=lane]
            float bv = (lane < 8) ? ldcv(&beta[b * Cz + cg * 8 + lane]) : 0.0f;
            #pragma unroll
            for (int j = 0; j < 8; j++) {
                int cc = cg * 8 + j;
                float e = enc[(size_t)(b * Cz + cc) * 64 + lane];
                float v = waveReduce(e * aval);
                float bj = __shfl(bv, j);
                if (lane == 0) xcat[b * 3072 + Ez + cc] = bj * v * (1.0f / 64.0f);
            }
            int gid = bid * NT + tid;
            if (gid < 8192) {
                int b2 = gid >> 10, r = gid & 1023;
                if (r < Ez) xcat[b2 * 3072 + r] = emb[(size_t)caps[b2 * T1z + t] * Ez + r];
                else        xcat[b2 * 3072 + 2560 + (r - Ez)] = ldcv(&hbuf[b2 * Dz + (r - Ez)]);
            }
        }
        gridSync(++bt);

        // ========== F: gates (LDS weights) + LSTM cell; xcat via 12-load asm batch ==========
        {
            float* gp = smem;               // partials: [8 waves][8 rows][8 b] = 512 floats
            const float4* wf4 = (const float4*)(smem + S_WF);
            int b = lane >> 3, e8 = lane & 7;
            const float4* xb = (const float4*)xcat + b * 768 + bw * 96 + e8;
            float4 xv[12];
            asm volatile(
                "global_load_dwordx4 %0,  %12, off sc0 sc1\n\t"
                "global_load_dwordx4 %1,  %12, off offset:128 sc0 sc1\n\t"
                "global_load_dwordx4 %2,  %12, off offset:256 sc0 sc1\n\t"
                "global_load_dwordx4 %3,  %12, off offset:384 sc0 sc1\n\t"
                "global_load_dwordx4 %4,  %12, off offset:512 sc0 sc1\n\t"
                "global_load_dwordx4 %5,  %12, off offset:640 sc0 sc1\n\t"
                "global_load_dwordx4 %6,  %12, off offset:768 sc0 sc1\n\t"
                "global_load_dwordx4 %7,  %12, off offset:896 sc0 sc1\n\t"
                "global_load_dwordx4 %8,  %12, off offset:1024 sc0 sc1\n\t"
                "global_load_dwordx4 %9,  %12, off offset:1152 sc0 sc1\n\t"
                "global_load_dwordx4 %10, %12, off offset:1280 sc0 sc1\n\t"
                "global_load_dwordx4 %11, %12, off offset:1408 sc0 sc1\n\t"
                "s_waitcnt vmcnt(0)"
                : "=&v"(xv[0]), "=&v"(xv[1]), "=&v"(xv[2]), "=&v"(xv[3]),
                  "=&v"(xv[4]), "=&v"(xv[5]), "=&v"(xv[6]), "=&v"(xv[7]),
                  "=&v"(xv[8]), "=&v"(xv[9]), "=&v"(xv[10]), "=&v"(xv[11])
                : "v"(xb) : "memory");
            float accg[8] = {0.f, 0.f, 0.f, 0.f, 0.f, 0.f, 0.f, 0.f};
            #pragma unroll
            for (int i = 0; i < 12; i++) {
                int ef4 = bw * 96 + i * 8 + e8;
                #pragma unroll
                for (int r2 = 0; r2 < 8; r2++) {
                    float4 w = wf4[r2 * 768 + ef4];
                    accg[r2] = fmaf(xv[i].x, w.x, accg[r2]);
                    accg[r2] = fmaf(xv[i].y, w.y, accg[r2]);
                    accg[r2] = fmaf(xv[i].z, w.z, accg[r2]);
                    accg[r2] = fmaf(xv[i].w, w.w, accg[r2]);
                }
            }
            #pragma unroll
            for (int mm = 1; mm < 8; mm <<= 1) {
                #pragma unroll
                for (int r2 = 0; r2 < 8; r2++) accg[r2] += __shfl_xor(accg[r2], mm);
            }
            if (e8 == 0) {
                #pragma unroll
                for (int r2 = 0; r2 < 8; r2++) gp[(bw * 8 + r2) * 8 + b] = accg[r2];
            }
            __syncthreads();
            if (tid < 16) {
                int b2 = tid & 7, ddd = tid >> 3;
                int d3 = bid * 2 + ddd;
                float gate[4];
                #pragma unroll
                for (int g = 0; g < 4; g++) {
                    float sum = 0.0f;
                    #pragma unroll
                    for (int qq = 0; qq < 8; qq++) sum += gp[(qq * 8 + g * 2 + ddd) * 8 + b2];
                    gate[g] = sum + b_ih[g * 512 + d3] + b_hh[g * 512 + d3];
                }
                int ci = b2 * 512 + d3;
                float cn = sigf(gate[1]) * ldcv(&cbuf[ci]) + sigf(gate[0]) * tanhf(gate[2]);
                cbuf[ci] = cn;
                float hn = sigf(gate[3]) * tanhf(cn);
                hbuf[ci] = hn;
                hhist[(t * 8 + b2) * 512 + d3] = hn;
            }
        }
        gridSync(++bt);
    }

    // ========== G: all predictions: out[96][20000] = h_hist @ W_fc^T ==========
    {
        int hr = bid & 1, vg = bid >> 1;
        if (vg < 125) {
            float4* hs4 = (float4*)smem;    // [48][128] f4 (aliases WF — t-loop done)
            const float4* hh4 = (const float4*)hhist + hr * 6144;
            #pragma unroll
            for (int i = 0; i < 12; i++) hs4[tid + i * 512] = hh4[tid + i * 512];
            __syncthreads();
            int r8 = lane >> 3, d8 = lane & 7;
            int v0 = vg * 160;
            #pragma unroll
            for (int bi = 0; bi < 2; bi++) {
                int vb = v0 + (bw * 2 + bi) * 10;
                float acc[10][6];
                #pragma unroll
                for (int vv = 0; vv < 10; vv++)
                    #pragma unroll
                    for (int rr = 0; rr < 6; rr++) acc[vv][rr] = 0.0f;
                for (int i = 0; i < 16; i++) {
                    float4 h6[6];
                    #pragma unroll
                    for (int rr = 0; rr < 6; rr++) h6[rr] = hs4[(r8 * 6 + rr) * 128 + i * 8 + d8];
                    #pragma unroll
                    for (int vv = 0; vv < 10; vv++) {
                        float4 w = ((const float4*)W_fc)[(size_t)(vb + vv) * 128 + i * 8 + d8];
                        #pragma unroll
                        for (int rr = 0; rr < 6; rr++) {
                            acc[vv][rr] = fmaf(w.x, h6[rr].x, acc[vv][rr]);
                            acc[vv][rr] = fmaf(w.y, h6[rr].y, acc[vv][rr]);
                            acc[vv][rr] = fmaf(w.z, h6[rr].z, acc[vv][rr]);
                            acc[vv][rr] = fmaf(w.w, h6[rr].w, acc[vv][rr]);
                        }
                    }
                }
                #pragma unroll
                for (int vv = 0; vv < 10; vv++) {
                    #pragma unroll
                    for (int rr = 0; rr < 6; rr++) {
                        float a = acc[vv][rr];
                        a += __shfl_xor(a, 1);
                        a += __shfl_xor(a, 2);
                        a += __shfl_xor(a, 4);
                        if (d8 == 0) {
                            int row = hr * 48 + r8 * 6 + rr;   // row = t*8 + b
                            int tt = row >> 3, b2 = row & 7;
                            out[((size_t)b2 * Tz + tt) * Vz + vb + vv] = a + b_fc[vb + vv];
                        }
                    }
                }
            }
        }
    }
}

extern "C" void kernel_launch(void* const* d_in, const int* in_sizes, int n_in,
                              void* d_out, int out_size, void* d_ws, size_t ws_size,
                              hipStream_t stream) {
    const float* enc      = (const float*)d_in[0];
    const int*   caps     = (const int*)d_in[1];
    const int*   caplen   = (const int*)d_in[2];
    const float* W_c      = (const float*)d_in[3];
    const float* W_hc     = (const float*)d_in[4];
    const float* W_i_hat  = (const float*)d_in[5];
    const float* b_c      = (const float*)d_in[6];
    const float* W_s      = (const float*)d_in[8];
    const float* W_hs     = (const float*)d_in[9];
    const float* W_i      = (const float*)d_in[10];
    const float* b_s      = (const float*)d_in[11];
    const float* emb      = (const float*)d_in[13];
    const float* W_ih     = (const float*)d_in[14];
    const float* W_hh     = (const float*)d_in[15];
    const float* b_ih     = (const float*)d_in[16];
    const float* b_hh     = (const float*)d_in[17];
    const float* W_init_h = (const float*)d_in[18];
    const float* b_init_h = (const float*)d_in[19];
    const float* W_init_c = (const float*)d_in[20];
    const float* b_init_c = (const float*)d_in[21];
    const float* W_fc     = (const float*)d_in[22];
    const float* b_fc     = (const float*)d_in[23];

    k_main<<<dim3(NB), dim3(NT), 0, stream>>>(
        enc, caps, caplen, W_c, b_c, W_i_hat, W_s, b_s, W_i, emb,
        W_ih, W_hh, b_ih, b_hh, W_init_h, b_init_h, W_init_c, b_init_c,
        W_hc, W_hs, W_fc, b_fc, (float*)d_out, (float*)d_ws);
}